// Round 3
// baseline (664.587 us; speedup 1.0000x reference)
//
#include <hip/hip_runtime.h>
#include <math.h>

typedef __bf16 bf16_t;
typedef __bf16 bf16x2 __attribute__((ext_vector_type(2)));
typedef __bf16 bf16x4 __attribute__((ext_vector_type(4)));
typedef __bf16 bf16x8 __attribute__((ext_vector_type(8)));
typedef float  f32x4  __attribute__((ext_vector_type(4)));

#define D_MODEL 1024
#define T_SEQ   2048
#define BATCH   2
#define NHEAD   16
#define DHEAD   64
#define DFF     4096
#define ROWS    (BATCH * T_SEQ)   // 4096

// ---------------- helpers ----------------
static __device__ __forceinline__ void gload_lds16(const void* g, void* l) {
  __builtin_amdgcn_global_load_lds((const __attribute__((address_space(1))) void*)g,
                                   (__attribute__((address_space(3))) void*)l,
                                   16, 0, 0);
}

// ---------------- f32 -> bf16 convert ----------------
__global__ __launch_bounds__(256) void cvt_bf16_kernel(const float* __restrict__ in,
                                                       bf16_t* __restrict__ out, int n) {
  int i = (blockIdx.x * 256 + threadIdx.x) * 4;
  if (i >= n) return;
  float4 v = *(const float4*)(in + i);
  bf16x4 o;
  o[0] = (bf16_t)v.x; o[1] = (bf16_t)v.y; o[2] = (bf16_t)v.z; o[3] = (bf16_t)v.w;
  *(bf16x4*)(out + i) = o;
}

// ---------------- RoPE tables ----------------
__global__ __launch_bounds__(256) void rope_tables_kernel(float* __restrict__ cost,
                                                          float* __restrict__ sint) {
  int i = blockIdx.x * 256 + threadIdx.x;      // T_SEQ*32
  int t = i >> 5, p = i & 31;
  double inv = pow(10000.0, -(double)(2 * p) / 64.0);
  double ang = (double)t * inv;
  cost[i] = (float)cos(ang);
  sint[i] = (float)sin(ang);
}

// ---------------- RMSNorm (f32 in, bf16 out) ----------------
__global__ __launch_bounds__(256) void rmsnorm_kernel(const float* __restrict__ x,
                                                      const float* __restrict__ g,
                                                      bf16_t* __restrict__ out) {
  const int row = blockIdx.x;
  const int tid = threadIdx.x;          // 256 threads * 4 floats = 1024
  const float4 v = ((const float4*)(x + (size_t)row * D_MODEL))[tid];
  float ss = v.x * v.x + v.y * v.y + v.z * v.z + v.w * v.w;
#pragma unroll
  for (int m = 32; m >= 1; m >>= 1) ss += __shfl_xor(ss, m);
  __shared__ float red[4];
  if ((tid & 63) == 0) red[tid >> 6] = ss;
  __syncthreads();
  float tot = red[0] + red[1] + red[2] + red[3];
  const float rinv = 1.0f / sqrtf(tot * (1.0f / D_MODEL) + 1e-5f);
  const float4 gv = ((const float4*)g)[tid];
  bf16x4 o;
  o[0] = (bf16_t)(v.x * rinv * gv.x);
  o[1] = (bf16_t)(v.y * rinv * gv.y);
  o[2] = (bf16_t)(v.z * rinv * gv.z);
  o[3] = (bf16_t)(v.w * rinv * gv.w);
  *(bf16x4*)(out + (size_t)row * D_MODEL + tid * 4) = o;
}

// ---------------- RoPE apply + scatter qkv -> Q,K [B*H,T,dh] ----------------
__global__ __launch_bounds__(256) void rope_scatter_kernel(const bf16_t* __restrict__ qkv,
                                                           const float* __restrict__ cost,
                                                           const float* __restrict__ sint,
                                                           bf16_t* __restrict__ Q,
                                                           bf16_t* __restrict__ K) {
  int i = blockIdx.x * 256 + threadIdx.x;  // B*T*H*32 = 2^21
  int p = i & 31;
  int h = (i >> 5) & 15;
  int t = (i >> 9) & 2047;
  int b = i >> 20;
  const bf16_t* base = qkv + (size_t)(b * T_SEQ + t) * (3 * D_MODEL) + h * DHEAD + 2 * p;
  float qe = (float)base[0],            qo = (float)base[1];
  float ke = (float)base[D_MODEL],      ko = (float)base[D_MODEL + 1];
  float c = cost[t * 32 + p], s = sint[t * 32 + p];
  size_t o = ((size_t)(b * NHEAD + h) * T_SEQ + t) * DHEAD + 2 * p;
  bf16x2 qv, kv;
  qv[0] = (bf16_t)(qe * c - qo * s); qv[1] = (bf16_t)(qe * s + qo * c);
  kv[0] = (bf16_t)(ke * c - ko * s); kv[1] = (bf16_t)(ke * s + ko * c);
  *(bf16x2*)(Q + o) = qv;
  *(bf16x2*)(K + o) = kv;
}

// ---------------- V transpose: qkv V-part -> Vt[bh][d][t] ----------------
__global__ __launch_bounds__(256) void vt_kernel(const bf16_t* __restrict__ qkv,
                                                 bf16_t* __restrict__ Vt) {
  __shared__ bf16_t ld[64 * 72];
  const int tid = threadIdx.x;
  const int tt = blockIdx.x;           // 0..31 t-tiles
  const int bh = blockIdx.y;           // 0..31
  const int b = bh >> 4, h = bh & 15;
#pragma unroll
  for (int it = 0; it < 2; ++it) {
    int idx = it * 256 + tid;          // 0..511
    int r = idx >> 3, cc = (idx & 7) * 8;
    bf16x8 v = *(const bf16x8*)&qkv[(size_t)(b * T_SEQ + tt * 64 + r) * (3 * D_MODEL)
                                    + 2 * D_MODEL + h * DHEAD + cc];
    *(bf16x8*)&ld[r * 72 + cc] = v;
  }
  __syncthreads();
#pragma unroll
  for (int it = 0; it < 2; ++it) {
    int idx = it * 256 + tid;
    int d = idx >> 3, t8 = (idx & 7) * 8;
    bf16x8 v;
#pragma unroll
    for (int j = 0; j < 8; ++j) v[j] = ld[(t8 + j) * 72 + d];
    *(bf16x8*)&Vt[((size_t)bh * DHEAD + d) * T_SEQ + tt * 64 + t8] = v;
  }
}

// ---------------- GEMM: C[M,N] = A[M,K] * B[N,K]^T  (+ res, f32 out) ----------------
// BK=64, 1-D grid with XCD swizzle (requires nwg % 8 == 0), 4 waves as 2x2.
template <int EPI, int BM, int BN>
__global__ __launch_bounds__(256) void gemm_bt(const bf16_t* __restrict__ A,
                                               const bf16_t* __restrict__ B,
                                               void* __restrict__ Cout,
                                               const float* __restrict__ res,
                                               int M, int N, int K, int gxn) {
  constexpr int MR = BM / 32, NR = BN / 32;
  __shared__ __align__(16) bf16_t lA[BM * 64];
  __shared__ __align__(16) bf16_t lB[BN * 64];
  const int tid = threadIdx.x;
  const int wave = tid >> 6, lane = tid & 63;
  const int lr = lane & 15, lg = lane >> 4;
  const int nwg = gridDim.x;
  const int bid = blockIdx.x;
  const int swz = (bid & 7) * (nwg >> 3) + (bid >> 3);
  const int bx = swz % gxn, by = swz / gxn;
  const int brow = by * BM, bcol = bx * BN;
  const int wr = (wave >> 1) * (BM / 2), wc = (wave & 1) * (BN / 2);
  f32x4 acc[MR][NR] = {};
  for (int k0 = 0; k0 < K; k0 += 64) {
    __syncthreads();  // protect LDS from previous iteration's readers
#pragma unroll
    for (int r = 0; r < BM / 32; ++r) {
      const int base = r * 4096 + wave * 1024;   // byte offset into A tile
      const int fb = base + lane * 16;
      const int row = fb >> 7;                   // 128B per row (64 bf16)
      const int e = (fb & 127) >> 1;
      gload_lds16(A + (size_t)(brow + row) * K + k0 + e, (char*)lA + base);
    }
#pragma unroll
    for (int r = 0; r < BN / 32; ++r) {
      const int base = r * 4096 + wave * 1024;
      const int fb = base + lane * 16;
      const int row = fb >> 7;
      const int e = (fb & 127) >> 1;
      gload_lds16(B + (size_t)(bcol + row) * K + k0 + e, (char*)lB + base);
    }
    __syncthreads();  // staging complete
    bf16x8 aF[MR][2], bF[NR][2];
#pragma unroll
    for (int mi = 0; mi < MR; ++mi)
#pragma unroll
      for (int h = 0; h < 2; ++h)
        aF[mi][h] = *(const bf16x8*)&lA[(wr + mi * 16 + lr) * 64 + h * 32 + 8 * lg];
#pragma unroll
    for (int ni = 0; ni < NR; ++ni)
#pragma unroll
      for (int h = 0; h < 2; ++h)
        bF[ni][h] = *(const bf16x8*)&lB[(wc + ni * 16 + lr) * 64 + h * 32 + 8 * lg];
#pragma unroll
    for (int h = 0; h < 2; ++h)
#pragma unroll
      for (int mi = 0; mi < MR; ++mi)
#pragma unroll
        for (int ni = 0; ni < NR; ++ni)
          acc[mi][ni] = __builtin_amdgcn_mfma_f32_16x16x32_bf16(aF[mi][h], bF[ni][h], acc[mi][ni], 0, 0, 0);
  }
  const int rb = brow + wr + lg * 4;
  const int cb = bcol + wc + lr;
  if (EPI == 0) {
    bf16_t* C = (bf16_t*)Cout;
#pragma unroll
    for (int mi = 0; mi < MR; ++mi)
#pragma unroll
      for (int ni = 0; ni < NR; ++ni)
#pragma unroll
        for (int i = 0; i < 4; ++i)
          C[(size_t)(rb + mi * 16 + i) * N + cb + ni * 16] = (bf16_t)acc[mi][ni][i];
  } else {
    float* C = (float*)Cout;
#pragma unroll
    for (int mi = 0; mi < MR; ++mi)
#pragma unroll
      for (int ni = 0; ni < NR; ++ni)
#pragma unroll
        for (int i = 0; i < 4; ++i) {
          size_t idx = (size_t)(rb + mi * 16 + i) * N + cb + ni * 16;
          C[idx] = acc[mi][ni][i] + res[idx];
        }
  }
}

// ---------------- causal flash attention v3 (swapped QK^T) ----------------
// Q,K: [B*H, T, 64] bf16; Vt: [B*H, 64, T] bf16. attn out: [B*T, 1024] bf16.
// 1024 blocks (XCD-grouped: 4 bh per XCD; long tiles first). Block = 4 waves,
// one 64-row q-tile; wave = 16 q rows. KV blocks of 64. Lane owns q-row = lr:
// scores s[c][i] = S[k = k0+c*16+lg*4+i][q = q0+lr]; softmax state is scalar.
// PV as mfma(Vt, P^T) keeps q = lr orientation (no broadcast shuffles).
__global__ __launch_bounds__(256) void attn_kernel(const bf16_t* __restrict__ Q,
                                                   const bf16_t* __restrict__ K,
                                                   const bf16_t* __restrict__ Vt,
                                                   bf16_t* __restrict__ attn) {
  __shared__ __align__(16) bf16_t pbuf[4][16 * 64];
  const int tid = threadIdx.x;
  const int wave = tid >> 6, lane = tid & 63;
  const int lr = lane & 15, lg = lane >> 4;
  const int bid = blockIdx.x;
  const int swz = (bid & 7) * 128 + (bid >> 3);
  const int bh = swz >> 5;
  const int tile = 31 - (swz & 31);          // long tiles dispatched first
  const int b = bh >> 4, hh = bh & 15;
  const size_t hb = (size_t)bh * T_SEQ * DHEAD;
  const bf16_t* Qb = Q + hb;
  const bf16_t* Kb = K + hb;
  const bf16_t* Vb = Vt + hb;                // [64][T]
  char* pwc = (char*)pbuf[wave];
  const int q0 = tile * 64 + wave * 16;

  bf16x8 qf[2];
#pragma unroll
  for (int h = 0; h < 2; ++h)
    qf[h] = *(const bf16x8*)&Qb[(size_t)(q0 + lr) * DHEAD + h * 32 + 8 * lg];
  f32x4 o[4] = {};
  float mrun = -INFINITY, lsum = 0.0f;

  for (int kb = 0; kb <= tile; ++kb) {
    const int k0 = kb * 64;
    f32x4 s[4] = {};
#pragma unroll
    for (int c = 0; c < 4; ++c) {
      const bf16_t* kp = &Kb[(size_t)(k0 + c * 16 + lr) * DHEAD + 8 * lg];
      bf16x8 kf0 = *(const bf16x8*)kp;
      bf16x8 kf1 = *(const bf16x8*)(kp + 32);
      s[c] = __builtin_amdgcn_mfma_f32_16x16x32_bf16(kf0, qf[0], s[c], 0, 0, 0);
      s[c] = __builtin_amdgcn_mfma_f32_16x16x32_bf16(kf1, qf[1], s[c], 0, 0, 0);
    }
    const bool dm = (k0 + 63 > q0);          // only the diagonal block masks
#pragma unroll
    for (int c = 0; c < 4; ++c)
#pragma unroll
      for (int i = 0; i < 4; ++i) {
        float v = s[c][i] * 0.125f;
        if (dm && (k0 + c * 16 + lg * 4 + i > q0 + lr)) v = -INFINITY;
        s[c][i] = v;
      }
    // row max for q = lr: 15 in-lane fmax + 2 shuffle rounds (lg groups)
    float bm = s[0][0];
#pragma unroll
    for (int c = 0; c < 4; ++c)
#pragma unroll
      for (int i = 0; i < 4; ++i) bm = fmaxf(bm, s[c][i]);
    bm = fmaxf(bm, __shfl_xor(bm, 16));
    bm = fmaxf(bm, __shfl_xor(bm, 32));
    const float mn = fmaxf(mrun, bm);
    const float al = __expf(mrun - mn);      // exp(-inf)=0 on first block
    mrun = mn;
    float bs = 0.0f;
#pragma unroll
    for (int c = 0; c < 4; ++c)
#pragma unroll
      for (int i = 0; i < 4; ++i) {
        float e = __expf(s[c][i] - mn);
        s[c][i] = e;
        bs += e;
      }
    bs += __shfl_xor(bs, 16);
    bs += __shfl_xor(bs, 32);
    lsum = lsum * al + bs;
#pragma unroll
    for (int dd = 0; dd < 4; ++dd)
#pragma unroll
      for (int i = 0; i < 4; ++i) o[dd][i] *= al;
    // P^T store: row q = lr, k = c*16 + lg*4 + i  (bf16x4, XOR-swizzled)
#pragma unroll
    for (int c = 0; c < 4; ++c) {
      bf16x4 pb;
#pragma unroll
      for (int i = 0; i < 4; ++i) pb[i] = (bf16_t)s[c][i];
      const int byt = (lr * 128 + c * 32 + lg * 8) ^ ((lr & 7) << 4);
      *(bf16x4*)(pwc + byt) = pb;
    }
    asm volatile("s_waitcnt lgkmcnt(0)" ::: "memory");
    __builtin_amdgcn_sched_barrier(0);
    bf16x8 pT[2];
#pragma unroll
    for (int h = 0; h < 2; ++h)
      pT[h] = *(const bf16x8*)(pwc + ((lr * 128 + h * 64 + lg * 16) ^ ((lr & 7) << 4)));
    // PV: o[dd] = mfma(Vt_frag, P^T_frag) -> rows d, cols q=lr
#pragma unroll
    for (int dd = 0; dd < 4; ++dd) {
      const bf16_t* vp = &Vb[(size_t)(dd * 16 + lr) * T_SEQ + k0 + 8 * lg];
      bf16x8 vf0 = *(const bf16x8*)vp;
      bf16x8 vf1 = *(const bf16x8*)(vp + 32);
      o[dd] = __builtin_amdgcn_mfma_f32_16x16x32_bf16(vf0, pT[0], o[dd], 0, 0, 0);
      o[dd] = __builtin_amdgcn_mfma_f32_16x16x32_bf16(vf1, pT[1], o[dd], 0, 0, 0);
    }
  }
  const float rls = 1.0f / lsum;
  bf16_t* orow = attn + (size_t)(b * T_SEQ + q0 + lr) * D_MODEL + hh * DHEAD;
#pragma unroll
  for (int dd = 0; dd < 4; ++dd) {
    bf16x4 ov;
#pragma unroll
    for (int i = 0; i < 4; ++i) ov[i] = (bf16_t)(o[dd][i] * rls);
    *(bf16x4*)(orow + dd * 16 + lg * 4) = ov;
  }
}

// ---------------- SwiGLU elementwise: a = silu(a) * b ----------------
__global__ __launch_bounds__(256) void swiglu_kernel(bf16_t* __restrict__ a,
                                                     const bf16_t* __restrict__ b) {
  size_t i = ((size_t)blockIdx.x * 256 + threadIdx.x) * 8;
  bf16x8 va = *(const bf16x8*)(a + i);
  bf16x8 vb = *(const bf16x8*)(b + i);
  bf16x8 og;
#pragma unroll
  for (int j = 0; j < 8; ++j) {
    float av = (float)va[j];
    float bv = (float)vb[j];
    float gv = av / (1.0f + __expf(-av)) * bv;
    og[j] = (bf16_t)gv;
  }
  *(bf16x8*)(a + i) = og;
}

// ---------------- launch ----------------
extern "C" void kernel_launch(void* const* d_in, const int* in_sizes, int n_in,
                              void* d_out, int out_size, void* d_ws, size_t ws_size,
                              hipStream_t stream) {
  const float* x    = (const float*)d_in[0];
  const float* Wqkv = (const float*)d_in[1];
  const float* Wo   = (const float*)d_in[2];
  const float* g1   = (const float*)d_in[3];
  const float* g2   = (const float*)d_in[4];
  const float* W1   = (const float*)d_in[5];
  const float* W2   = (const float*)d_in[6];
  const float* W3   = (const float*)d_in[7];
  float* out = (float*)d_out;
  char* ws = (char*)d_ws;
  const size_t MB = 1024 * 1024;

  // workspace map (regions overlapped by liveness):
  float*  x1   = (float*)(ws + 0);          // [0,16M)  f32 residual-1 output
  bf16_t* h    = (bf16_t*)(ws + 16 * MB);   // [16,24M) rmsnorm1 out
  bf16_t* attn = (bf16_t*)(ws + 16 * MB);   // reuse (h dead after QKV gemm)
  bf16_t* h2   = (bf16_t*)(ws + 16 * MB);   // reuse (attn dead after Wo gemm)
  bf16_t* qkv  = (bf16_t*)(ws + 24 * MB);   // [24,48M)
  bf16_t* Qb   = (bf16_t*)(ws + 48 * MB);   // [48,56M)
  bf16_t* Kb   = (bf16_t*)(ws + 56 * MB);   // [56,64M)
  bf16_t* Vt   = (bf16_t*)(ws + 64 * MB);   // [64,72M)  V^T [bh][d][t]
  bf16_t* abuf = (bf16_t*)(ws + 24 * MB);   // [24,56M) reuse (qkv,Q dead)
  bf16_t* bbuf = (bf16_t*)(ws + 56 * MB);   // [56,88M) reuse (K,Vt dead)
  float*  cost = (float*)(ws + 88 * MB);
  float*  sint = (float*)(ws + 88 * MB + 262144);
  bf16_t* wq_b = (bf16_t*)(ws + 89 * MB);   // 6M
  bf16_t* wo_b = (bf16_t*)(ws + 95 * MB);   // 2M
  bf16_t* w1_b = (bf16_t*)(ws + 97 * MB);   // 8M
  bf16_t* w3_b = (bf16_t*)(ws + 105 * MB);  // 8M
  bf16_t* w2_b = (bf16_t*)(ws + 113 * MB);  // 8M  -> peak 121M

  // weight conversion
  cvt_bf16_kernel<<<3 * D_MODEL * D_MODEL / 1024, 256, 0, stream>>>(Wqkv, wq_b, 3 * D_MODEL * D_MODEL);
  cvt_bf16_kernel<<<D_MODEL * D_MODEL / 1024, 256, 0, stream>>>(Wo, wo_b, D_MODEL * D_MODEL);
  cvt_bf16_kernel<<<DFF * D_MODEL / 1024, 256, 0, stream>>>(W1, w1_b, DFF * D_MODEL);
  cvt_bf16_kernel<<<DFF * D_MODEL / 1024, 256, 0, stream>>>(W3, w3_b, DFF * D_MODEL);
  cvt_bf16_kernel<<<DFF * D_MODEL / 1024, 256, 0, stream>>>(W2, w2_b, DFF * D_MODEL);
  rope_tables_kernel<<<(T_SEQ * 32) / 256, 256, 0, stream>>>(cost, sint);

  // attention sub-block
  rmsnorm_kernel<<<ROWS, 256, 0, stream>>>(x, g1, h);
  gemm_bt<0, 128, 128><<<768, 256, 0, stream>>>(h, wq_b, qkv, nullptr,
                                                ROWS, 3 * D_MODEL, D_MODEL, 24);
  rope_scatter_kernel<<<(BATCH * T_SEQ * NHEAD * 32) / 256, 256, 0, stream>>>(
      qkv, cost, sint, Qb, Kb);
  vt_kernel<<<dim3(T_SEQ / 64, BATCH * NHEAD), 256, 0, stream>>>(qkv, Vt);
  attn_kernel<<<1024, 256, 0, stream>>>(Qb, Kb, Vt, attn);
  gemm_bt<1, 64, 64><<<1024, 256, 0, stream>>>(attn, wo_b, x1, x,
                                               ROWS, D_MODEL, D_MODEL, 16);

  // FFN sub-block
  rmsnorm_kernel<<<ROWS, 256, 0, stream>>>(x1, g2, h2);
  gemm_bt<0, 128, 128><<<1024, 256, 0, stream>>>(h2, w1_b, abuf, nullptr,
                                                 ROWS, DFF, D_MODEL, 32);
  gemm_bt<0, 128, 128><<<1024, 256, 0, stream>>>(h2, w3_b, bbuf, nullptr,
                                                 ROWS, DFF, D_MODEL, 32);
  swiglu_kernel<<<(ROWS * DFF) / (256 * 8), 256, 0, stream>>>(abuf, bbuf);
  gemm_bt<1, 64, 64><<<1024, 256, 0, stream>>>(abuf, w2_b, out, x1,
                                               ROWS, D_MODEL, DFF, 16);
}

// Round 4
// 583.549 us; speedup vs baseline: 1.1389x; 1.1389x over previous
//
#include <hip/hip_runtime.h>
#include <math.h>

typedef __bf16 bf16_t;
typedef __bf16 bf16x2 __attribute__((ext_vector_type(2)));
typedef __bf16 bf16x4 __attribute__((ext_vector_type(4)));
typedef __bf16 bf16x8 __attribute__((ext_vector_type(8)));
typedef float  f32x4  __attribute__((ext_vector_type(4)));

#define D_MODEL 1024
#define T_SEQ   2048
#define BATCH   2
#define NHEAD   16
#define DHEAD   64
#define DFF     4096
#define ROWS    (BATCH * T_SEQ)   // 4096

// ---------------- helpers ----------------
static __device__ __forceinline__ void gload_lds16(const void* g, void* l) {
  __builtin_amdgcn_global_load_lds((const __attribute__((address_space(1))) void*)g,
                                   (__attribute__((address_space(3))) void*)l,
                                   16, 0, 0);
}

// ---------------- f32 -> bf16 convert ----------------
__global__ __launch_bounds__(256) void cvt_bf16_kernel(const float* __restrict__ in,
                                                       bf16_t* __restrict__ out, int n) {
  int i = (blockIdx.x * 256 + threadIdx.x) * 4;
  if (i >= n) return;
  float4 v = *(const float4*)(in + i);
  bf16x4 o;
  o[0] = (bf16_t)v.x; o[1] = (bf16_t)v.y; o[2] = (bf16_t)v.z; o[3] = (bf16_t)v.w;
  *(bf16x4*)(out + i) = o;
}

// ---------------- RoPE tables ----------------
__global__ __launch_bounds__(256) void rope_tables_kernel(float* __restrict__ cost,
                                                          float* __restrict__ sint) {
  int i = blockIdx.x * 256 + threadIdx.x;      // T_SEQ*32
  int t = i >> 5, p = i & 31;
  double inv = pow(10000.0, -(double)(2 * p) / 64.0);
  double ang = (double)t * inv;
  cost[i] = (float)cos(ang);
  sint[i] = (float)sin(ang);
}

// ---------------- RMSNorm (f32 in, bf16 out) ----------------
__global__ __launch_bounds__(256) void rmsnorm_kernel(const float* __restrict__ x,
                                                      const float* __restrict__ g,
                                                      bf16_t* __restrict__ out) {
  const int row = blockIdx.x;
  const int tid = threadIdx.x;          // 256 threads * 4 floats = 1024
  const float4 v = ((const float4*)(x + (size_t)row * D_MODEL))[tid];
  float ss = v.x * v.x + v.y * v.y + v.z * v.z + v.w * v.w;
#pragma unroll
  for (int m = 32; m >= 1; m >>= 1) ss += __shfl_xor(ss, m);
  __shared__ float red[4];
  if ((tid & 63) == 0) red[tid >> 6] = ss;
  __syncthreads();
  float tot = red[0] + red[1] + red[2] + red[3];
  const float rinv = 1.0f / sqrtf(tot * (1.0f / D_MODEL) + 1e-5f);
  const float4 gv = ((const float4*)g)[tid];
  bf16x4 o;
  o[0] = (bf16_t)(v.x * rinv * gv.x);
  o[1] = (bf16_t)(v.y * rinv * gv.y);
  o[2] = (bf16_t)(v.z * rinv * gv.z);
  o[3] = (bf16_t)(v.w * rinv * gv.w);
  *(bf16x4*)(out + (size_t)row * D_MODEL + tid * 4) = o;
}

// ---------------- RoPE apply + scatter qkv -> Q,K [B*H,T,dh] ----------------
__global__ __launch_bounds__(256) void rope_scatter_kernel(const bf16_t* __restrict__ qkv,
                                                           const float* __restrict__ cost,
                                                           const float* __restrict__ sint,
                                                           bf16_t* __restrict__ Q,
                                                           bf16_t* __restrict__ K) {
  int i = blockIdx.x * 256 + threadIdx.x;  // B*T*H*32 = 2^21
  int p = i & 31;
  int h = (i >> 5) & 15;
  int t = (i >> 9) & 2047;
  int b = i >> 20;
  const bf16_t* base = qkv + (size_t)(b * T_SEQ + t) * (3 * D_MODEL) + h * DHEAD + 2 * p;
  float qe = (float)base[0],            qo = (float)base[1];
  float ke = (float)base[D_MODEL],      ko = (float)base[D_MODEL + 1];
  float c = cost[t * 32 + p], s = sint[t * 32 + p];
  size_t o = ((size_t)(b * NHEAD + h) * T_SEQ + t) * DHEAD + 2 * p;
  bf16x2 qv, kv;
  qv[0] = (bf16_t)(qe * c - qo * s); qv[1] = (bf16_t)(qe * s + qo * c);
  kv[0] = (bf16_t)(ke * c - ko * s); kv[1] = (bf16_t)(ke * s + ko * c);
  *(bf16x2*)(Q + o) = qv;
  *(bf16x2*)(K + o) = kv;
}

// ---------------- V transpose: qkv V-part -> Vt[bh][t64][d][64] (tiled) -----
__global__ __launch_bounds__(256) void vt_kernel(const bf16_t* __restrict__ qkv,
                                                 bf16_t* __restrict__ Vt) {
  __shared__ bf16_t ld[64 * 72];
  const int tid = threadIdx.x;
  const int tt = blockIdx.x;           // 0..31 t-tiles
  const int bh = blockIdx.y;           // 0..31
  const int b = bh >> 4, h = bh & 15;
#pragma unroll
  for (int it = 0; it < 2; ++it) {
    int idx = it * 256 + tid;          // 0..511
    int r = idx >> 3, cc = (idx & 7) * 8;
    bf16x8 v = *(const bf16x8*)&qkv[(size_t)(b * T_SEQ + tt * 64 + r) * (3 * D_MODEL)
                                    + 2 * D_MODEL + h * DHEAD + cc];
    *(bf16x8*)&ld[r * 72 + cc] = v;
  }
  __syncthreads();
#pragma unroll
  for (int it = 0; it < 2; ++it) {
    int idx = it * 256 + tid;
    int d = idx >> 3, t8 = (idx & 7) * 8;
    bf16x8 v;
#pragma unroll
    for (int j = 0; j < 8; ++j) v[j] = ld[(t8 + j) * 72 + d];
    *(bf16x8*)&Vt[(((size_t)bh * 32 + tt) * 64 + d) * 64 + t8] = v;
  }
}

// ---------------- GEMM: C[M,N] = A[M,K] * B[N,K]^T  (+ res, f32 out) ----------------
// BK=64, 1-D grid with XCD swizzle (requires nwg % 8 == 0), 4 waves as 2x2.
template <int EPI, int BM, int BN>
__global__ __launch_bounds__(256) void gemm_bt(const bf16_t* __restrict__ A,
                                               const bf16_t* __restrict__ B,
                                               void* __restrict__ Cout,
                                               const float* __restrict__ res,
                                               int M, int N, int K, int gxn) {
  constexpr int MR = BM / 32, NR = BN / 32;
  __shared__ __align__(16) bf16_t lA[BM * 64];
  __shared__ __align__(16) bf16_t lB[BN * 64];
  const int tid = threadIdx.x;
  const int wave = tid >> 6, lane = tid & 63;
  const int lr = lane & 15, lg = lane >> 4;
  const int nwg = gridDim.x;
  const int bid = blockIdx.x;
  const int swz = (bid & 7) * (nwg >> 3) + (bid >> 3);
  const int bx = swz % gxn, by = swz / gxn;
  const int brow = by * BM, bcol = bx * BN;
  const int wr = (wave >> 1) * (BM / 2), wc = (wave & 1) * (BN / 2);
  f32x4 acc[MR][NR] = {};
  for (int k0 = 0; k0 < K; k0 += 64) {
    __syncthreads();  // protect LDS from previous iteration's readers
#pragma unroll
    for (int r = 0; r < BM / 32; ++r) {
      const int base = r * 4096 + wave * 1024;   // byte offset into A tile
      const int fb = base + lane * 16;
      const int row = fb >> 7;                   // 128B per row (64 bf16)
      const int e = (fb & 127) >> 1;
      gload_lds16(A + (size_t)(brow + row) * K + k0 + e, (char*)lA + base);
    }
#pragma unroll
    for (int r = 0; r < BN / 32; ++r) {
      const int base = r * 4096 + wave * 1024;
      const int fb = base + lane * 16;
      const int row = fb >> 7;
      const int e = (fb & 127) >> 1;
      gload_lds16(B + (size_t)(bcol + row) * K + k0 + e, (char*)lB + base);
    }
    __syncthreads();  // staging complete
    bf16x8 aF[MR][2], bF[NR][2];
#pragma unroll
    for (int mi = 0; mi < MR; ++mi)
#pragma unroll
      for (int h = 0; h < 2; ++h)
        aF[mi][h] = *(const bf16x8*)&lA[(wr + mi * 16 + lr) * 64 + h * 32 + 8 * lg];
#pragma unroll
    for (int ni = 0; ni < NR; ++ni)
#pragma unroll
      for (int h = 0; h < 2; ++h)
        bF[ni][h] = *(const bf16x8*)&lB[(wc + ni * 16 + lr) * 64 + h * 32 + 8 * lg];
#pragma unroll
    for (int h = 0; h < 2; ++h)
#pragma unroll
      for (int mi = 0; mi < MR; ++mi)
#pragma unroll
        for (int ni = 0; ni < NR; ++ni)
          acc[mi][ni] = __builtin_amdgcn_mfma_f32_16x16x32_bf16(aF[mi][h], bF[ni][h], acc[mi][ni], 0, 0, 0);
  }
  const int rb = brow + wr + lg * 4;
  const int cb = bcol + wc + lr;
  if (EPI == 0) {
    bf16_t* C = (bf16_t*)Cout;
#pragma unroll
    for (int mi = 0; mi < MR; ++mi)
#pragma unroll
      for (int ni = 0; ni < NR; ++ni)
#pragma unroll
        for (int i = 0; i < 4; ++i)
          C[(size_t)(rb + mi * 16 + i) * N + cb + ni * 16] = (bf16_t)acc[mi][ni][i];
  } else {
    float* C = (float*)Cout;
#pragma unroll
    for (int mi = 0; mi < MR; ++mi)
#pragma unroll
      for (int ni = 0; ni < NR; ++ni)
#pragma unroll
        for (int i = 0; i < 4; ++i) {
          size_t idx = (size_t)(rb + mi * 16 + i) * N + cb + ni * 16;
          C[idx] = acc[mi][ni][i] + res[idx];
        }
  }
}

// ---------------- causal flash attention v4 ----------------
// Q,K: [B*H, T, 64] bf16; Vt: [B*H][32][64][64] (t64-tiled, d-major) bf16.
// attn out: [B*T, 1024] bf16. Grid 1024 blocks x 4 waves (16 waves/CU).
// bid -> XCD-grouped bh (L2-resident K/Vt) + hashed tile (CU load spread).
// Swapped QK^T (lane owns q-row = lr); KVBLK = 128 (one softmax reduction +
// one LDS P round-trip per 128 keys); T13 defer-max.
__global__ __launch_bounds__(256, 4) void attn_kernel(const bf16_t* __restrict__ Q,
                                                      const bf16_t* __restrict__ K,
                                                      const bf16_t* __restrict__ Vt,
                                                      bf16_t* __restrict__ attn) {
  __shared__ __align__(16) bf16_t pbuf[4][16 * 128];
  const int tid = threadIdx.x;
  const int wave = tid >> 6, lane = tid & 63;
  const int lr = lane & 15, lg = lane >> 4;
  const int bid = blockIdx.x;
  const int x = bid & 7, u = bid >> 3;       // u: 0..127
  const int bh = x * 4 + (u & 3);            // XCD x owns bh 4x..4x+3
  const int v = u >> 2;                      // 0..31
  const int tile = (7 * v + 5 * (u & 3) + x) & 31;   // hashed bijection per bh
  const int b = bh >> 4, hh = bh & 15;
  const size_t hb = (size_t)bh * T_SEQ * DHEAD;
  const bf16_t* Qb = Q + hb;
  const bf16_t* Kb = K + hb;
  const bf16_t* Vb = Vt + hb;                // [32][64][64]
  char* pwc = (char*)pbuf[wave];
  const int q0 = tile * 64 + wave * 16;
  const int xo = (lr & 15) << 4;             // LDS XOR swizzle for this row

  bf16x8 qf[2];
#pragma unroll
  for (int h = 0; h < 2; ++h)
    qf[h] = *(const bf16x8*)&Qb[(size_t)(q0 + lr) * DHEAD + h * 32 + 8 * lg];
  f32x4 o[4] = {};
  float mrun = -INFINITY, lsum = 0.0f;
  const int nit = (q0 + 16 + 127) >> 7;      // 128-key blocks covering q0+15

  for (int it = 0; it < nit; ++it) {
    const int k0 = it * 128;
    f32x4 s[8] = {};
#pragma unroll
    for (int c = 0; c < 8; ++c) {
      const bf16_t* kp = &Kb[(size_t)(k0 + c * 16 + lr) * DHEAD + 8 * lg];
      bf16x8 kf0 = *(const bf16x8*)kp;
      bf16x8 kf1 = *(const bf16x8*)(kp + 32);
      s[c] = __builtin_amdgcn_mfma_f32_16x16x32_bf16(kf0, qf[0], s[c], 0, 0, 0);
      s[c] = __builtin_amdgcn_mfma_f32_16x16x32_bf16(kf1, qf[1], s[c], 0, 0, 0);
    }
    const bool dm = (k0 + 127 > q0);         // masking needed this block
#pragma unroll
    for (int c = 0; c < 8; ++c)
#pragma unroll
      for (int i = 0; i < 4; ++i) {
        float sv = s[c][i] * 0.125f;
        if (dm && (k0 + c * 16 + lg * 4 + i > q0 + lr)) sv = -INFINITY;
        s[c][i] = sv;
      }
    // row max for q = lr: 31 in-lane fmax + 2 shuffle rounds (lg groups)
    float bm = s[0][0];
#pragma unroll
    for (int c = 0; c < 8; ++c)
#pragma unroll
      for (int i = 0; i < 4; ++i) bm = fmaxf(bm, s[c][i]);
    bm = fmaxf(bm, __shfl_xor(bm, 16));
    bm = fmaxf(bm, __shfl_xor(bm, 32));
    if (!__all(bm <= mrun)) {                // T13 defer-max
      const float mn = fmaxf(mrun, bm);
      const float al = __expf(mrun - mn);    // exp(-inf)=0 on first block
      mrun = mn;
      lsum *= al;
#pragma unroll
      for (int dd = 0; dd < 4; ++dd)
#pragma unroll
        for (int i = 0; i < 4; ++i) o[dd][i] *= al;
    }
    float bs = 0.0f;
#pragma unroll
    for (int c = 0; c < 8; ++c)
#pragma unroll
      for (int i = 0; i < 4; ++i) {
        float e = __expf(s[c][i] - mrun);
        s[c][i] = e;
        bs += e;
      }
    bs += __shfl_xor(bs, 16);
    bs += __shfl_xor(bs, 32);
    lsum += bs;
    // P^T store: row q = lr (256B), k = c*16 + lg*4 + i  (bf16x4, XOR-swizzled)
#pragma unroll
    for (int c = 0; c < 8; ++c) {
      bf16x4 pb;
#pragma unroll
      for (int i = 0; i < 4; ++i) pb[i] = (bf16_t)s[c][i];
      const int byt = (lr * 256 + c * 32 + lg * 8) ^ xo;
      *(bf16x4*)(pwc + byt) = pb;
    }
    asm volatile("s_waitcnt lgkmcnt(0)" ::: "memory");
    __builtin_amdgcn_sched_barrier(0);
    bf16x8 pT[4];
#pragma unroll
    for (int h = 0; h < 4; ++h)
      pT[h] = *(const bf16x8*)(pwc + ((lr * 256 + h * 64 + lg * 16) ^ xo));
    // PV: o[dd] = sum_h mfma(Vt_frag(h), P^T_frag(h)); rows d, cols q=lr
#pragma unroll
    for (int dd = 0; dd < 4; ++dd) {
#pragma unroll
      for (int h = 0; h < 4; ++h) {
        const bf16_t* vp = &Vb[(((size_t)(k0 >> 6) + (h >> 1)) * 64 + dd * 16 + lr) * 64
                               + (h & 1) * 32 + 8 * lg];
        bf16x8 vf = *(const bf16x8*)vp;
        o[dd] = __builtin_amdgcn_mfma_f32_16x16x32_bf16(vf, pT[h], o[dd], 0, 0, 0);
      }
    }
  }
  const float rls = 1.0f / lsum;
  bf16_t* orow = attn + (size_t)(b * T_SEQ + q0 + lr) * D_MODEL + hh * DHEAD;
#pragma unroll
  for (int dd = 0; dd < 4; ++dd) {
    bf16x4 ov;
#pragma unroll
    for (int i = 0; i < 4; ++i) ov[i] = (bf16_t)(o[dd][i] * rls);
    *(bf16x4*)(orow + dd * 16 + lg * 4) = ov;
  }
}

// ---------------- SwiGLU elementwise: a = silu(a) * b ----------------
__global__ __launch_bounds__(256) void swiglu_kernel(bf16_t* __restrict__ a,
                                                     const bf16_t* __restrict__ b) {
  size_t i = ((size_t)blockIdx.x * 256 + threadIdx.x) * 8;
  bf16x8 va = *(const bf16x8*)(a + i);
  bf16x8 vb = *(const bf16x8*)(b + i);
  bf16x8 og;
#pragma unroll
  for (int j = 0; j < 8; ++j) {
    float av = (float)va[j];
    float bv = (float)vb[j];
    float gv = av / (1.0f + __expf(-av)) * bv;
    og[j] = (bf16_t)gv;
  }
  *(bf16x8*)(a + i) = og;
}

// ---------------- launch ----------------
extern "C" void kernel_launch(void* const* d_in, const int* in_sizes, int n_in,
                              void* d_out, int out_size, void* d_ws, size_t ws_size,
                              hipStream_t stream) {
  const float* x    = (const float*)d_in[0];
  const float* Wqkv = (const float*)d_in[1];
  const float* Wo   = (const float*)d_in[2];
  const float* g1   = (const float*)d_in[3];
  const float* g2   = (const float*)d_in[4];
  const float* W1   = (const float*)d_in[5];
  const float* W2   = (const float*)d_in[6];
  const float* W3   = (const float*)d_in[7];
  float* out = (float*)d_out;
  char* ws = (char*)d_ws;
  const size_t MB = 1024 * 1024;

  // workspace map (regions overlapped by liveness):
  float*  x1   = (float*)(ws + 0);          // [0,16M)  f32 residual-1 output
  bf16_t* h    = (bf16_t*)(ws + 16 * MB);   // [16,24M) rmsnorm1 out
  bf16_t* attn = (bf16_t*)(ws + 16 * MB);   // reuse (h dead after QKV gemm)
  bf16_t* h2   = (bf16_t*)(ws + 16 * MB);   // reuse (attn dead after Wo gemm)
  bf16_t* qkv  = (bf16_t*)(ws + 24 * MB);   // [24,48M)
  bf16_t* Qb   = (bf16_t*)(ws + 48 * MB);   // [48,56M)
  bf16_t* Kb   = (bf16_t*)(ws + 56 * MB);   // [56,64M)
  bf16_t* Vt   = (bf16_t*)(ws + 64 * MB);   // [64,72M)  V tiled [bh][t64][d][64]
  bf16_t* abuf = (bf16_t*)(ws + 24 * MB);   // [24,56M) reuse (qkv,Q dead)
  bf16_t* bbuf = (bf16_t*)(ws + 56 * MB);   // [56,88M) reuse (K,Vt dead)
  float*  cost = (float*)(ws + 88 * MB);
  float*  sint = (float*)(ws + 88 * MB + 262144);
  bf16_t* wq_b = (bf16_t*)(ws + 89 * MB);   // 6M
  bf16_t* wo_b = (bf16_t*)(ws + 95 * MB);   // 2M
  bf16_t* w1_b = (bf16_t*)(ws + 97 * MB);   // 8M
  bf16_t* w3_b = (bf16_t*)(ws + 105 * MB);  // 8M
  bf16_t* w2_b = (bf16_t*)(ws + 113 * MB);  // 8M  -> peak 121M

  // weight conversion
  cvt_bf16_kernel<<<3 * D_MODEL * D_MODEL / 1024, 256, 0, stream>>>(Wqkv, wq_b, 3 * D_MODEL * D_MODEL);
  cvt_bf16_kernel<<<D_MODEL * D_MODEL / 1024, 256, 0, stream>>>(Wo, wo_b, D_MODEL * D_MODEL);
  cvt_bf16_kernel<<<DFF * D_MODEL / 1024, 256, 0, stream>>>(W1, w1_b, DFF * D_MODEL);
  cvt_bf16_kernel<<<DFF * D_MODEL / 1024, 256, 0, stream>>>(W3, w3_b, DFF * D_MODEL);
  cvt_bf16_kernel<<<DFF * D_MODEL / 1024, 256, 0, stream>>>(W2, w2_b, DFF * D_MODEL);
  rope_tables_kernel<<<(T_SEQ * 32) / 256, 256, 0, stream>>>(cost, sint);

  // attention sub-block
  rmsnorm_kernel<<<ROWS, 256, 0, stream>>>(x, g1, h);
  gemm_bt<0, 128, 128><<<768, 256, 0, stream>>>(h, wq_b, qkv, nullptr,
                                                ROWS, 3 * D_MODEL, D_MODEL, 24);
  rope_scatter_kernel<<<(BATCH * T_SEQ * NHEAD * 32) / 256, 256, 0, stream>>>(
      qkv, cost, sint, Qb, Kb);
  vt_kernel<<<dim3(T_SEQ / 64, BATCH * NHEAD), 256, 0, stream>>>(qkv, Vt);
  attn_kernel<<<1024, 256, 0, stream>>>(Qb, Kb, Vt, attn);
  gemm_bt<1, 64, 64><<<1024, 256, 0, stream>>>(attn, wo_b, x1, x,
                                               ROWS, D_MODEL, D_MODEL, 16);

  // FFN sub-block
  rmsnorm_kernel<<<ROWS, 256, 0, stream>>>(x1, g2, h2);
  gemm_bt<0, 128, 128><<<1024, 256, 0, stream>>>(h2, w1_b, abuf, nullptr,
                                                 ROWS, DFF, D_MODEL, 32);
  gemm_bt<0, 128, 128><<<1024, 256, 0, stream>>>(h2, w3_b, bbuf, nullptr,
                                                 ROWS, DFF, D_MODEL, 32);
  swiglu_kernel<<<(ROWS * DFF) / (256 * 8), 256, 0, stream>>>(abuf, bbuf);
  gemm_bt<1, 64, 64><<<1024, 256, 0, stream>>>(abuf, w2_b, out, x1,
                                               ROWS, D_MODEL, DFF, 16);
}

// Round 5
// 494.657 us; speedup vs baseline: 1.3435x; 1.1797x over previous
//
#include <hip/hip_runtime.h>
#include <math.h>

typedef __bf16 bf16_t;
typedef __bf16 bf16x2 __attribute__((ext_vector_type(2)));
typedef __bf16 bf16x4 __attribute__((ext_vector_type(4)));
typedef __bf16 bf16x8 __attribute__((ext_vector_type(8)));
typedef float  f32x4  __attribute__((ext_vector_type(4)));

#define D_MODEL 1024
#define T_SEQ   2048
#define BATCH   2
#define NHEAD   16
#define DHEAD   64
#define DFF     4096
#define ROWS    (BATCH * T_SEQ)   // 4096

// ---------------- helpers ----------------
static __device__ __forceinline__ void gload_lds16(const void* g, void* l) {
  __builtin_amdgcn_global_load_lds((const __attribute__((address_space(1))) void*)g,
                                   (__attribute__((address_space(3))) void*)l,
                                   16, 0, 0);
}

// ---------------- f32 -> bf16 convert ----------------
__global__ __launch_bounds__(256) void cvt_bf16_kernel(const float* __restrict__ in,
                                                       bf16_t* __restrict__ out, int n) {
  int i = (blockIdx.x * 256 + threadIdx.x) * 4;
  if (i >= n) return;
  float4 v = *(const float4*)(in + i);
  bf16x4 o;
  o[0] = (bf16_t)v.x; o[1] = (bf16_t)v.y; o[2] = (bf16_t)v.z; o[3] = (bf16_t)v.w;
  *(bf16x4*)(out + i) = o;
}

// ---------------- RoPE tables ----------------
__global__ __launch_bounds__(256) void rope_tables_kernel(float* __restrict__ cost,
                                                          float* __restrict__ sint) {
  int i = blockIdx.x * 256 + threadIdx.x;      // T_SEQ*32
  int t = i >> 5, p = i & 31;
  double inv = pow(10000.0, -(double)(2 * p) / 64.0);
  double ang = (double)t * inv;
  cost[i] = (float)cos(ang);
  sint[i] = (float)sin(ang);
}

// ---------------- RMSNorm (f32 in, bf16 out) ----------------
__global__ __launch_bounds__(256) void rmsnorm_kernel(const float* __restrict__ x,
                                                      const float* __restrict__ g,
                                                      bf16_t* __restrict__ out) {
  const int row = blockIdx.x;
  const int tid = threadIdx.x;          // 256 threads * 4 floats = 1024
  const float4 v = ((const float4*)(x + (size_t)row * D_MODEL))[tid];
  float ss = v.x * v.x + v.y * v.y + v.z * v.z + v.w * v.w;
#pragma unroll
  for (int m = 32; m >= 1; m >>= 1) ss += __shfl_xor(ss, m);
  __shared__ float red[4];
  if ((tid & 63) == 0) red[tid >> 6] = ss;
  __syncthreads();
  float tot = red[0] + red[1] + red[2] + red[3];
  const float rinv = 1.0f / sqrtf(tot * (1.0f / D_MODEL) + 1e-5f);
  const float4 gv = ((const float4*)g)[tid];
  bf16x4 o;
  o[0] = (bf16_t)(v.x * rinv * gv.x);
  o[1] = (bf16_t)(v.y * rinv * gv.y);
  o[2] = (bf16_t)(v.z * rinv * gv.z);
  o[3] = (bf16_t)(v.w * rinv * gv.w);
  *(bf16x4*)(out + (size_t)row * D_MODEL + tid * 4) = o;
}

// ---------------- RoPE apply + scatter qkv -> Q,K [B*H,T,dh] ----------------
__global__ __launch_bounds__(256) void rope_scatter_kernel(const bf16_t* __restrict__ qkv,
                                                           const float* __restrict__ cost,
                                                           const float* __restrict__ sint,
                                                           bf16_t* __restrict__ Q,
                                                           bf16_t* __restrict__ K) {
  int i = blockIdx.x * 256 + threadIdx.x;  // B*T*H*32 = 2^21
  int p = i & 31;
  int h = (i >> 5) & 15;
  int t = (i >> 9) & 2047;
  int b = i >> 20;
  const bf16_t* base = qkv + (size_t)(b * T_SEQ + t) * (3 * D_MODEL) + h * DHEAD + 2 * p;
  float qe = (float)base[0],            qo = (float)base[1];
  float ke = (float)base[D_MODEL],      ko = (float)base[D_MODEL + 1];
  float c = cost[t * 32 + p], s = sint[t * 32 + p];
  size_t o = ((size_t)(b * NHEAD + h) * T_SEQ + t) * DHEAD + 2 * p;
  bf16x2 qv, kv;
  qv[0] = (bf16_t)(qe * c - qo * s); qv[1] = (bf16_t)(qe * s + qo * c);
  kv[0] = (bf16_t)(ke * c - ko * s); kv[1] = (bf16_t)(ke * s + ko * c);
  *(bf16x2*)(Q + o) = qv;
  *(bf16x2*)(K + o) = kv;
}

// ---------------- V transpose: qkv V-part -> Vt[bh][t64][d][64] (tiled) -----
__global__ __launch_bounds__(256) void vt_kernel(const bf16_t* __restrict__ qkv,
                                                 bf16_t* __restrict__ Vt) {
  __shared__ bf16_t ld[64 * 72];
  const int tid = threadIdx.x;
  const int tt = blockIdx.x;           // 0..31 t-tiles
  const int bh = blockIdx.y;           // 0..31
  const int b = bh >> 4, h = bh & 15;
#pragma unroll
  for (int it = 0; it < 2; ++it) {
    int idx = it * 256 + tid;          // 0..511
    int r = idx >> 3, cc = (idx & 7) * 8;
    bf16x8 v = *(const bf16x8*)&qkv[(size_t)(b * T_SEQ + tt * 64 + r) * (3 * D_MODEL)
                                    + 2 * D_MODEL + h * DHEAD + cc];
    *(bf16x8*)&ld[r * 72 + cc] = v;
  }
  __syncthreads();
#pragma unroll
  for (int it = 0; it < 2; ++it) {
    int idx = it * 256 + tid;
    int d = idx >> 3, t8 = (idx & 7) * 8;
    bf16x8 v;
#pragma unroll
    for (int j = 0; j < 8; ++j) v[j] = ld[(t8 + j) * 72 + d];
    *(bf16x8*)&Vt[(((size_t)bh * 32 + tt) * 64 + d) * 64 + t8] = v;
  }
}

// ---------------- GEMM: C[M,N] = A[M,K] * B[N,K]^T  (+ res, f32 out) ----------------
// BK=64, 1-D grid with XCD swizzle (requires nwg % 8 == 0), 4 waves as 2x2.
template <int EPI, int BM, int BN>
__global__ __launch_bounds__(256) void gemm_bt(const bf16_t* __restrict__ A,
                                               const bf16_t* __restrict__ B,
                                               void* __restrict__ Cout,
                                               const float* __restrict__ res,
                                               int M, int N, int K, int gxn) {
  constexpr int MR = BM / 32, NR = BN / 32;
  __shared__ __align__(16) bf16_t lA[BM * 64];
  __shared__ __align__(16) bf16_t lB[BN * 64];
  const int tid = threadIdx.x;
  const int wave = tid >> 6, lane = tid & 63;
  const int lr = lane & 15, lg = lane >> 4;
  const int nwg = gridDim.x;
  const int bid = blockIdx.x;
  const int swz = (bid & 7) * (nwg >> 3) + (bid >> 3);
  const int bx = swz % gxn, by = swz / gxn;
  const int brow = by * BM, bcol = bx * BN;
  const int wr = (wave >> 1) * (BM / 2), wc = (wave & 1) * (BN / 2);
  f32x4 acc[MR][NR] = {};
  for (int k0 = 0; k0 < K; k0 += 64) {
    __syncthreads();  // protect LDS from previous iteration's readers
#pragma unroll
    for (int r = 0; r < BM / 32; ++r) {
      const int base = r * 4096 + wave * 1024;   // byte offset into A tile
      const int fb = base + lane * 16;
      const int row = fb >> 7;                   // 128B per row (64 bf16)
      const int e = (fb & 127) >> 1;
      gload_lds16(A + (size_t)(brow + row) * K + k0 + e, (char*)lA + base);
    }
#pragma unroll
    for (int r = 0; r < BN / 32; ++r) {
      const int base = r * 4096 + wave * 1024;
      const int fb = base + lane * 16;
      const int row = fb >> 7;
      const int e = (fb & 127) >> 1;
      gload_lds16(B + (size_t)(bcol + row) * K + k0 + e, (char*)lB + base);
    }
    __syncthreads();  // staging complete
    bf16x8 aF[MR][2], bF[NR][2];
#pragma unroll
    for (int mi = 0; mi < MR; ++mi)
#pragma unroll
      for (int h = 0; h < 2; ++h)
        aF[mi][h] = *(const bf16x8*)&lA[(wr + mi * 16 + lr) * 64 + h * 32 + 8 * lg];
#pragma unroll
    for (int ni = 0; ni < NR; ++ni)
#pragma unroll
      for (int h = 0; h < 2; ++h)
        bF[ni][h] = *(const bf16x8*)&lB[(wc + ni * 16 + lr) * 64 + h * 32 + 8 * lg];
#pragma unroll
    for (int h = 0; h < 2; ++h)
#pragma unroll
      for (int mi = 0; mi < MR; ++mi)
#pragma unroll
        for (int ni = 0; ni < NR; ++ni)
          acc[mi][ni] = __builtin_amdgcn_mfma_f32_16x16x32_bf16(aF[mi][h], bF[ni][h], acc[mi][ni], 0, 0, 0);
  }
  const int rb = brow + wr + lg * 4;
  const int cb = bcol + wc + lr;
  if (EPI == 0) {
    bf16_t* C = (bf16_t*)Cout;
#pragma unroll
    for (int mi = 0; mi < MR; ++mi)
#pragma unroll
      for (int ni = 0; ni < NR; ++ni)
#pragma unroll
        for (int i = 0; i < 4; ++i)
          C[(size_t)(rb + mi * 16 + i) * N + cb + ni * 16] = (bf16_t)acc[mi][ni][i];
  } else {
    float* C = (float*)Cout;
#pragma unroll
    for (int mi = 0; mi < MR; ++mi)
#pragma unroll
      for (int ni = 0; ni < NR; ++ni)
#pragma unroll
        for (int i = 0; i < 4; ++i) {
          size_t idx = (size_t)(rb + mi * 16 + i) * N + cb + ni * 16;
          C[idx] = acc[mi][ni][i] + res[idx];
        }
  }
}

// ---------------- causal flash attention v5 (LDS-staged K/V, dbuf) ----------
// Q,K: [B*H, T, 64] bf16; Vt: [B*H][32][64][64] (t64-tiled, [d][t]) bf16.
// Grid 1024 blocks x 4 waves. bid -> XCD-grouped bh + hashed tile.
// KVBLK=64. K/V double-buffered in LDS via global_load_lds (async): stage
// tile it+1 at top of iter it; the per-iter __syncthreads drains vmcnt.
// LDS layout: linear dest + inverse-swizzled global source + swizzled reads
// (byte ^ ((row&7)<<4)) -> conflict-free ds_read_b128 (rule #21 / T2).
// Swapped QK^T: lane owns q-row = lr; softmax state scalar; T13 defer-max.
__global__ __launch_bounds__(256, 4) void attn_kernel(const bf16_t* __restrict__ Q,
                                                      const bf16_t* __restrict__ K,
                                                      const bf16_t* __restrict__ Vt,
                                                      bf16_t* __restrict__ attn) {
  __shared__ __align__(16) bf16_t kbuf[2][64 * 64];
  __shared__ __align__(16) bf16_t vbuf[2][64 * 64];
  __shared__ __align__(16) bf16_t pbuf[4][16 * 64];
  const int tid = threadIdx.x;
  const int wave = tid >> 6, lane = tid & 63;
  const int lr = lane & 15, lg = lane >> 4;
  const int bid = blockIdx.x;
  const int x = bid & 7, u = bid >> 3;       // u: 0..127
  const int bh = x * 4 + (u & 3);            // XCD x owns bh 4x..4x+3
  const int v = u >> 2;                      // 0..31
  const int tile = (7 * v + 5 * (u & 3) + x) & 31;   // hashed bijection per bh
  const int b = bh >> 4, hh = bh & 15;
  const size_t hb = (size_t)bh * T_SEQ * DHEAD;
  const bf16_t* Qb = Q + hb;
  const bf16_t* Kb = K + hb;
  const bf16_t* Vb = Vt + hb;                // [32][64][64]
  char* pwc = (char*)pbuf[wave];
  const int q0 = tile * 64 + wave * 16;
  // staging: this wave's 2 chunks of each 8KB tile; inverse-swizzled source
  const int c0 = wave * 2, c1 = wave * 2 + 1;
  const int so = (lane * 16) ^ ((lane >> 3) << 4);   // within-chunk src byte

  bf16x8 qf[2];
#pragma unroll
  for (int h = 0; h < 2; ++h)
    qf[h] = *(const bf16x8*)&Qb[(size_t)(q0 + lr) * DHEAD + h * 32 + 8 * lg];
  f32x4 o[4] = {};
  float mrun = -INFINITY, lsum = 0.0f;
  const int nit = tile + 1;                  // 64-key blocks (uniform over waves)

  // prologue: stage tile 0 into buffer 0
  {
    const char* kg = (const char*)Kb;        // rows 0..63 contiguous 8KB
    const char* vg = (const char*)Vb;        // tile 0 [d][t] contiguous 8KB
    gload_lds16(kg + c0 * 1024 + so, (char*)kbuf[0] + c0 * 1024);
    gload_lds16(kg + c1 * 1024 + so, (char*)kbuf[0] + c1 * 1024);
    gload_lds16(vg + c0 * 1024 + so, (char*)vbuf[0] + c0 * 1024);
    gload_lds16(vg + c1 * 1024 + so, (char*)vbuf[0] + c1 * 1024);
  }
  __syncthreads();
  int cur = 0;

  for (int it = 0; it < nit; ++it) {
    const int k0 = it * 64;
    if (it + 1 < nit) {                      // async-prefetch next tile
      const char* kg = (const char*)(Kb + (size_t)(k0 + 64) * DHEAD);
      const char* vg = (const char*)(Vb + (size_t)(it + 1) * 4096);
      char* kd = (char*)kbuf[cur ^ 1];
      char* vd = (char*)vbuf[cur ^ 1];
      gload_lds16(kg + c0 * 1024 + so, kd + c0 * 1024);
      gload_lds16(kg + c1 * 1024 + so, kd + c1 * 1024);
      gload_lds16(vg + c0 * 1024 + so, vd + c0 * 1024);
      gload_lds16(vg + c1 * 1024 + so, vd + c1 * 1024);
    }
    const char* kl = (const char*)kbuf[cur];
    const char* vl = (const char*)vbuf[cur];
    // QK^T from LDS (swizzled reads)
    f32x4 s[4] = {};
#pragma unroll
    for (int c = 0; c < 4; ++c) {
      const int tr = c * 16 + lr;
      const int sw = (tr & 7) << 4;
      bf16x8 kf0 = *(const bf16x8*)(kl + tr * 128 + ((16 * lg) ^ sw));
      bf16x8 kf1 = *(const bf16x8*)(kl + tr * 128 + ((64 + 16 * lg) ^ sw));
      s[c] = __builtin_amdgcn_mfma_f32_16x16x32_bf16(kf0, qf[0], s[c], 0, 0, 0);
      s[c] = __builtin_amdgcn_mfma_f32_16x16x32_bf16(kf1, qf[1], s[c], 0, 0, 0);
    }
    const bool dm = (k0 + 63 > q0);          // only the diagonal block masks
#pragma unroll
    for (int c = 0; c < 4; ++c)
#pragma unroll
      for (int i = 0; i < 4; ++i) {
        float sv = s[c][i] * 0.125f;
        if (dm && (k0 + c * 16 + lg * 4 + i > q0 + lr)) sv = -INFINITY;
        s[c][i] = sv;
      }
    // row max for q = lr: 15 in-lane fmax + 2 shuffle rounds (lg groups)
    float bm = s[0][0];
#pragma unroll
    for (int c = 0; c < 4; ++c)
#pragma unroll
      for (int i = 0; i < 4; ++i) bm = fmaxf(bm, s[c][i]);
    bm = fmaxf(bm, __shfl_xor(bm, 16));
    bm = fmaxf(bm, __shfl_xor(bm, 32));
    if (!__all(bm <= mrun)) {                // T13 defer-max
      const float mn = fmaxf(mrun, bm);
      const float al = __expf(mrun - mn);    // exp(-inf)=0 on first block
      mrun = mn;
      lsum *= al;
#pragma unroll
      for (int dd = 0; dd < 4; ++dd)
#pragma unroll
        for (int i = 0; i < 4; ++i) o[dd][i] *= al;
    }
    float bs = 0.0f;
#pragma unroll
    for (int c = 0; c < 4; ++c)
#pragma unroll
      for (int i = 0; i < 4; ++i) {
        float e = __expf(s[c][i] - mrun);
        s[c][i] = e;
        bs += e;
      }
    bs += __shfl_xor(bs, 16);
    bs += __shfl_xor(bs, 32);
    lsum += bs;
    // P^T store: row q = lr (128B), k = c*16 + lg*4 + i  (bf16x4, XOR-swizzled)
#pragma unroll
    for (int c = 0; c < 4; ++c) {
      bf16x4 pb;
#pragma unroll
      for (int i = 0; i < 4; ++i) pb[i] = (bf16_t)s[c][i];
      const int byt = (lr * 128 + ((c * 32 + lg * 8) ^ ((lr & 7) << 4)));
      *(bf16x4*)(pwc + byt) = pb;
    }
    asm volatile("s_waitcnt lgkmcnt(0)" ::: "memory");
    __builtin_amdgcn_sched_barrier(0);
    bf16x8 pT[2];
#pragma unroll
    for (int h = 0; h < 2; ++h)
      pT[h] = *(const bf16x8*)(pwc + (lr * 128 + ((h * 64 + 16 * lg) ^ ((lr & 7) << 4))));
    // PV from LDS V tile ([d][t], swizzled reads): rows d, cols q=lr
#pragma unroll
    for (int dd = 0; dd < 4; ++dd) {
      const int vr = dd * 16 + lr;
      const int sw = (vr & 7) << 4;
      bf16x8 vf0 = *(const bf16x8*)(vl + vr * 128 + ((16 * lg) ^ sw));
      bf16x8 vf1 = *(const bf16x8*)(vl + vr * 128 + ((64 + 16 * lg) ^ sw));
      o[dd] = __builtin_amdgcn_mfma_f32_16x16x32_bf16(vf0, pT[0], o[dd], 0, 0, 0);
      o[dd] = __builtin_amdgcn_mfma_f32_16x16x32_bf16(vf1, pT[1], o[dd], 0, 0, 0);
    }
    __syncthreads();                         // drains vmcnt -> next buffer ready
    cur ^= 1;
  }
  const float rls = 1.0f / lsum;
  bf16_t* orow = attn + (size_t)(b * T_SEQ + q0 + lr) * D_MODEL + hh * DHEAD;
#pragma unroll
  for (int dd = 0; dd < 4; ++dd) {
    bf16x4 ov;
#pragma unroll
    for (int i = 0; i < 4; ++i) ov[i] = (bf16_t)(o[dd][i] * rls);
    *(bf16x4*)(orow + dd * 16 + lg * 4) = ov;
  }
}

// ---------------- SwiGLU elementwise: a = silu(a) * b ----------------
__global__ __launch_bounds__(256) void swiglu_kernel(bf16_t* __restrict__ a,
                                                     const bf16_t* __restrict__ b) {
  size_t i = ((size_t)blockIdx.x * 256 + threadIdx.x) * 8;
  bf16x8 va = *(const bf16x8*)(a + i);
  bf16x8 vb = *(const bf16x8*)(b + i);
  bf16x8 og;
#pragma unroll
  for (int j = 0; j < 8; ++j) {
    float av = (float)va[j];
    float bv = (float)vb[j];
    float gv = av / (1.0f + __expf(-av)) * bv;
    og[j] = (bf16_t)gv;
  }
  *(bf16x8*)(a + i) = og;
}

// ---------------- launch ----------------
extern "C" void kernel_launch(void* const* d_in, const int* in_sizes, int n_in,
                              void* d_out, int out_size, void* d_ws, size_t ws_size,
                              hipStream_t stream) {
  const float* x    = (const float*)d_in[0];
  const float* Wqkv = (const float*)d_in[1];
  const float* Wo   = (const float*)d_in[2];
  const float* g1   = (const float*)d_in[3];
  const float* g2   = (const float*)d_in[4];
  const float* W1   = (const float*)d_in[5];
  const float* W2   = (const float*)d_in[6];
  const float* W3   = (const float*)d_in[7];
  float* out = (float*)d_out;
  char* ws = (char*)d_ws;
  const size_t MB = 1024 * 1024;

  // workspace map (regions overlapped by liveness):
  float*  x1   = (float*)(ws + 0);          // [0,16M)  f32 residual-1 output
  bf16_t* h    = (bf16_t*)(ws + 16 * MB);   // [16,24M) rmsnorm1 out
  bf16_t* attn = (bf16_t*)(ws + 16 * MB);   // reuse (h dead after QKV gemm)
  bf16_t* h2   = (bf16_t*)(ws + 16 * MB);   // reuse (attn dead after Wo gemm)
  bf16_t* qkv  = (bf16_t*)(ws + 24 * MB);   // [24,48M)
  bf16_t* Qb   = (bf16_t*)(ws + 48 * MB);   // [48,56M)
  bf16_t* Kb   = (bf16_t*)(ws + 56 * MB);   // [56,64M)
  bf16_t* Vt   = (bf16_t*)(ws + 64 * MB);   // [64,72M)  V tiled [bh][t64][d][64]
  bf16_t* abuf = (bf16_t*)(ws + 24 * MB);   // [24,56M) reuse (qkv,Q dead)
  bf16_t* bbuf = (bf16_t*)(ws + 56 * MB);   // [56,88M) reuse (K,Vt dead)
  float*  cost = (float*)(ws + 88 * MB);
  float*  sint = (float*)(ws + 88 * MB + 262144);
  bf16_t* wq_b = (bf16_t*)(ws + 89 * MB);   // 6M
  bf16_t* wo_b = (bf16_t*)(ws + 95 * MB);   // 2M
  bf16_t* w1_b = (bf16_t*)(ws + 97 * MB);   // 8M
  bf16_t* w3_b = (bf16_t*)(ws + 105 * MB);  // 8M
  bf16_t* w2_b = (bf16_t*)(ws + 113 * MB);  // 8M  -> peak 121M

  // weight conversion
  cvt_bf16_kernel<<<3 * D_MODEL * D_MODEL / 1024, 256, 0, stream>>>(Wqkv, wq_b, 3 * D_MODEL * D_MODEL);
  cvt_bf16_kernel<<<D_MODEL * D_MODEL / 1024, 256, 0, stream>>>(Wo, wo_b, D_MODEL * D_MODEL);
  cvt_bf16_kernel<<<DFF * D_MODEL / 1024, 256, 0, stream>>>(W1, w1_b, DFF * D_MODEL);
  cvt_bf16_kernel<<<DFF * D_MODEL / 1024, 256, 0, stream>>>(W3, w3_b, DFF * D_MODEL);
  cvt_bf16_kernel<<<DFF * D_MODEL / 1024, 256, 0, stream>>>(W2, w2_b, DFF * D_MODEL);
  rope_tables_kernel<<<(T_SEQ * 32) / 256, 256, 0, stream>>>(cost, sint);

  // attention sub-block
  rmsnorm_kernel<<<ROWS, 256, 0, stream>>>(x, g1, h);
  gemm_bt<0, 128, 128><<<768, 256, 0, stream>>>(h, wq_b, qkv, nullptr,
                                                ROWS, 3 * D_MODEL, D_MODEL, 24);
  rope_scatter_kernel<<<(BATCH * T_SEQ * NHEAD * 32) / 256, 256, 0, stream>>>(
      qkv, cost, sint, Qb, Kb);
  vt_kernel<<<dim3(T_SEQ / 64, BATCH * NHEAD), 256, 0, stream>>>(qkv, Vt);
  attn_kernel<<<1024, 256, 0, stream>>>(Qb, Kb, Vt, attn);
  gemm_bt<1, 64, 64><<<1024, 256, 0, stream>>>(attn, wo_b, x1, x,
                                               ROWS, D_MODEL, D_MODEL, 16);

  // FFN sub-block
  rmsnorm_kernel<<<ROWS, 256, 0, stream>>>(x1, g2, h2);
  gemm_bt<0, 128, 128><<<1024, 256, 0, stream>>>(h2, w1_b, abuf, nullptr,
                                                 ROWS, DFF, D_MODEL, 32);
  gemm_bt<0, 128, 128><<<1024, 256, 0, stream>>>(h2, w3_b, bbuf, nullptr,
                                                 ROWS, DFF, D_MODEL, 32);
  swiglu_kernel<<<(ROWS * DFF) / (256 * 8), 256, 0, stream>>>(abuf, bbuf);
  gemm_bt<1, 64, 64><<<1024, 256, 0, stream>>>(abuf, w2_b, out, x1,
                                               ROWS, D_MODEL, DFF, 16);
}

// Round 6
// 473.719 us; speedup vs baseline: 1.4029x; 1.0442x over previous
//
#include <hip/hip_runtime.h>
#include <math.h>

typedef __bf16 bf16_t;
typedef __bf16 bf16x2 __attribute__((ext_vector_type(2)));
typedef __bf16 bf16x4 __attribute__((ext_vector_type(4)));
typedef __bf16 bf16x8 __attribute__((ext_vector_type(8)));
typedef float  f32x4  __attribute__((ext_vector_type(4)));

#define D_MODEL 1024
#define T_SEQ   2048
#define BATCH   2
#define NHEAD   16
#define DHEAD   64
#define DFF     4096
#define ROWS    (BATCH * T_SEQ)   // 4096

// ---------------- helpers ----------------
static __device__ __forceinline__ void gload_lds16(const void* g, void* l) {
  __builtin_amdgcn_global_load_lds((const __attribute__((address_space(1))) void*)g,
                                   (__attribute__((address_space(3))) void*)l,
                                   16, 0, 0);
}

// ---------------- fused f32 -> bf16 weight convert ----------------
// ranges in 4-float groups: Wqkv 786432 | Wo 262144 | W1 1048576 | W3 1048576 | W2 1048576
__global__ __launch_bounds__(256) void cvt_all_kernel(const float* __restrict__ Wqkv,
                                                      const float* __restrict__ Wo,
                                                      const float* __restrict__ W1,
                                                      const float* __restrict__ W3,
                                                      const float* __restrict__ W2,
                                                      bf16_t* __restrict__ wq,
                                                      bf16_t* __restrict__ wo,
                                                      bf16_t* __restrict__ w13,
                                                      bf16_t* __restrict__ w2) {
  int i = blockIdx.x * 256 + threadIdx.x;   // 4194304 groups total
  const float* src; bf16_t* dst; int off;
  if (i < 786432)       { src = Wqkv; dst = wq;            off = i; }
  else if (i < 1048576) { src = Wo;   dst = wo;            off = i - 786432; }
  else if (i < 2097152) { src = W1;   dst = w13;           off = i - 1048576; }
  else if (i < 3145728) { src = W3;   dst = w13 + 4194304; off = i - 2097152; }
  else                  { src = W2;   dst = w2;            off = i - 3145728; }
  float4 v = ((const float4*)src)[off];
  bf16x4 o;
  o[0] = (bf16_t)v.x; o[1] = (bf16_t)v.y; o[2] = (bf16_t)v.z; o[3] = (bf16_t)v.w;
  *(bf16x4*)(dst + off * 4) = o;
}

// ---------------- RoPE tables ----------------
__global__ __launch_bounds__(256) void rope_tables_kernel(float* __restrict__ cost,
                                                          float* __restrict__ sint) {
  int i = blockIdx.x * 256 + threadIdx.x;      // T_SEQ*32
  int t = i >> 5, p = i & 31;
  double inv = pow(10000.0, -(double)(2 * p) / 64.0);
  double ang = (double)t * inv;
  cost[i] = (float)cos(ang);
  sint[i] = (float)sin(ang);
}

// ---------------- RMSNorm (f32 in, bf16 out) ----------------
__global__ __launch_bounds__(256) void rmsnorm_kernel(const float* __restrict__ x,
                                                      const float* __restrict__ g,
                                                      bf16_t* __restrict__ out) {
  const int row = blockIdx.x;
  const int tid = threadIdx.x;          // 256 threads * 4 floats = 1024
  const float4 v = ((const float4*)(x + (size_t)row * D_MODEL))[tid];
  float ss = v.x * v.x + v.y * v.y + v.z * v.z + v.w * v.w;
#pragma unroll
  for (int m = 32; m >= 1; m >>= 1) ss += __shfl_xor(ss, m);
  __shared__ float red[4];
  if ((tid & 63) == 0) red[tid >> 6] = ss;
  __syncthreads();
  float tot = red[0] + red[1] + red[2] + red[3];
  const float rinv = 1.0f / sqrtf(tot * (1.0f / D_MODEL) + 1e-5f);
  const float4 gv = ((const float4*)g)[tid];
  bf16x4 o;
  o[0] = (bf16_t)(v.x * rinv * gv.x);
  o[1] = (bf16_t)(v.y * rinv * gv.y);
  o[2] = (bf16_t)(v.z * rinv * gv.z);
  o[3] = (bf16_t)(v.w * rinv * gv.w);
  *(bf16x4*)(out + (size_t)row * D_MODEL + tid * 4) = o;
}

// ---------------- RoPE apply + scatter qkv -> Q,K [B*H,T,dh] ----------------
__global__ __launch_bounds__(256) void rope_scatter_kernel(const bf16_t* __restrict__ qkv,
                                                           const float* __restrict__ cost,
                                                           const float* __restrict__ sint,
                                                           bf16_t* __restrict__ Q,
                                                           bf16_t* __restrict__ K) {
  int i = blockIdx.x * 256 + threadIdx.x;  // B*T*H*32 = 2^21
  int p = i & 31;
  int h = (i >> 5) & 15;
  int t = (i >> 9) & 2047;
  int b = i >> 20;
  const bf16_t* base = qkv + (size_t)(b * T_SEQ + t) * (3 * D_MODEL) + h * DHEAD + 2 * p;
  float qe = (float)base[0],            qo = (float)base[1];
  float ke = (float)base[D_MODEL],      ko = (float)base[D_MODEL + 1];
  float c = cost[t * 32 + p], s = sint[t * 32 + p];
  size_t o = ((size_t)(b * NHEAD + h) * T_SEQ + t) * DHEAD + 2 * p;
  bf16x2 qv, kv;
  qv[0] = (bf16_t)(qe * c - qo * s); qv[1] = (bf16_t)(qe * s + qo * c);
  kv[0] = (bf16_t)(ke * c - ko * s); kv[1] = (bf16_t)(ke * s + ko * c);
  *(bf16x2*)(Q + o) = qv;
  *(bf16x2*)(K + o) = kv;
}

// ---------------- V transpose: qkv V-part -> Vt[bh][t64][d][64] (tiled) -----
__global__ __launch_bounds__(256) void vt_kernel(const bf16_t* __restrict__ qkv,
                                                 bf16_t* __restrict__ Vt) {
  __shared__ bf16_t ld[64 * 72];
  const int tid = threadIdx.x;
  const int tt = blockIdx.x;           // 0..31 t-tiles
  const int bh = blockIdx.y;           // 0..31
  const int b = bh >> 4, h = bh & 15;
#pragma unroll
  for (int it = 0; it < 2; ++it) {
    int idx = it * 256 + tid;          // 0..511
    int r = idx >> 3, cc = (idx & 7) * 8;
    bf16x8 v = *(const bf16x8*)&qkv[(size_t)(b * T_SEQ + tt * 64 + r) * (3 * D_MODEL)
                                    + 2 * D_MODEL + h * DHEAD + cc];
    *(bf16x8*)&ld[r * 72 + cc] = v;
  }
  __syncthreads();
#pragma unroll
  for (int it = 0; it < 2; ++it) {
    int idx = it * 256 + tid;
    int d = idx >> 3, t8 = (idx & 7) * 8;
    bf16x8 v;
#pragma unroll
    for (int j = 0; j < 8; ++j) v[j] = ld[(t8 + j) * 72 + d];
    *(bf16x8*)&Vt[(((size_t)bh * 32 + tt) * 64 + d) * 64 + t8] = v;
  }
}

// ---------------- GEMM: C[M,N] = A[M,K] * B[N,K]^T  (+ res, f32 out) ----------------
// BK=64, 1-D grid with XCD swizzle (requires nwg % 8 == 0), 4 waves as 2x2.
// lda = A row stride in elements (>=K; supports packed multi-purpose buffers).
template <int EPI, int BM, int BN>
__global__ __launch_bounds__(256) void gemm_bt(const bf16_t* __restrict__ A,
                                               const bf16_t* __restrict__ B,
                                               void* __restrict__ Cout,
                                               const float* __restrict__ res,
                                               int M, int N, int K, int lda, int gxn) {
  constexpr int MR = BM / 32, NR = BN / 32;
  __shared__ __align__(16) bf16_t lA[BM * 64];
  __shared__ __align__(16) bf16_t lB[BN * 64];
  const int tid = threadIdx.x;
  const int wave = tid >> 6, lane = tid & 63;
  const int lr = lane & 15, lg = lane >> 4;
  const int nwg = gridDim.x;
  const int bid = blockIdx.x;
  const int swz = (bid & 7) * (nwg >> 3) + (bid >> 3);
  const int bx = swz % gxn, by = swz / gxn;
  const int brow = by * BM, bcol = bx * BN;
  const int wr = (wave >> 1) * (BM / 2), wc = (wave & 1) * (BN / 2);
  f32x4 acc[MR][NR] = {};
  for (int k0 = 0; k0 < K; k0 += 64) {
    __syncthreads();  // protect LDS from previous iteration's readers
#pragma unroll
    for (int r = 0; r < BM / 32; ++r) {
      const int base = r * 4096 + wave * 1024;   // byte offset into A tile
      const int fb = base + lane * 16;
      const int row = fb >> 7;                   // 128B per row (64 bf16)
      const int e = (fb & 127) >> 1;
      gload_lds16(A + (size_t)(brow + row) * lda + k0 + e, (char*)lA + base);
    }
#pragma unroll
    for (int r = 0; r < BN / 32; ++r) {
      const int base = r * 4096 + wave * 1024;
      const int fb = base + lane * 16;
      const int row = fb >> 7;
      const int e = (fb & 127) >> 1;
      gload_lds16(B + (size_t)(bcol + row) * K + k0 + e, (char*)lB + base);
    }
    __syncthreads();  // staging complete
    bf16x8 aF[MR][2], bF[NR][2];
#pragma unroll
    for (int mi = 0; mi < MR; ++mi)
#pragma unroll
      for (int h = 0; h < 2; ++h)
        aF[mi][h] = *(const bf16x8*)&lA[(wr + mi * 16 + lr) * 64 + h * 32 + 8 * lg];
#pragma unroll
    for (int ni = 0; ni < NR; ++ni)
#pragma unroll
      for (int h = 0; h < 2; ++h)
        bF[ni][h] = *(const bf16x8*)&lB[(wc + ni * 16 + lr) * 64 + h * 32 + 8 * lg];
#pragma unroll
    for (int h = 0; h < 2; ++h)
#pragma unroll
      for (int mi = 0; mi < MR; ++mi)
#pragma unroll
        for (int ni = 0; ni < NR; ++ni)
          acc[mi][ni] = __builtin_amdgcn_mfma_f32_16x16x32_bf16(aF[mi][h], bF[ni][h], acc[mi][ni], 0, 0, 0);
  }
  const int rb = brow + wr + lg * 4;
  const int cb = bcol + wc + lr;
  if (EPI == 0) {
    bf16_t* C = (bf16_t*)Cout;
#pragma unroll
    for (int mi = 0; mi < MR; ++mi)
#pragma unroll
      for (int ni = 0; ni < NR; ++ni)
#pragma unroll
        for (int i = 0; i < 4; ++i)
          C[(size_t)(rb + mi * 16 + i) * N + cb + ni * 16] = (bf16_t)acc[mi][ni][i];
  } else {
    float* C = (float*)Cout;
#pragma unroll
    for (int mi = 0; mi < MR; ++mi)
#pragma unroll
      for (int ni = 0; ni < NR; ++ni)
#pragma unroll
        for (int i = 0; i < 4; ++i) {
          size_t idx = (size_t)(rb + mi * 16 + i) * N + cb + ni * 16;
          C[idx] = acc[mi][ni][i] + res[idx];
        }
  }
}

// ---------------- causal flash attention v5 (LDS-staged K/V, dbuf) ----------
__global__ __launch_bounds__(256, 4) void attn_kernel(const bf16_t* __restrict__ Q,
                                                      const bf16_t* __restrict__ K,
                                                      const bf16_t* __restrict__ Vt,
                                                      bf16_t* __restrict__ attn) {
  __shared__ __align__(16) bf16_t kbuf[2][64 * 64];
  __shared__ __align__(16) bf16_t vbuf[2][64 * 64];
  __shared__ __align__(16) bf16_t pbuf[4][16 * 64];
  const int tid = threadIdx.x;
  const int wave = tid >> 6, lane = tid & 63;
  const int lr = lane & 15, lg = lane >> 4;
  const int bid = blockIdx.x;
  const int x = bid & 7, u = bid >> 3;       // u: 0..127
  const int bh = x * 4 + (u & 3);            // XCD x owns bh 4x..4x+3
  const int v = u >> 2;                      // 0..31
  const int tile = (7 * v + 5 * (u & 3) + x) & 31;   // hashed bijection per bh
  const int b = bh >> 4, hh = bh & 15;
  const size_t hb = (size_t)bh * T_SEQ * DHEAD;
  const bf16_t* Qb = Q + hb;
  const bf16_t* Kb = K + hb;
  const bf16_t* Vb = Vt + hb;                // [32][64][64]
  char* pwc = (char*)pbuf[wave];
  const int q0 = tile * 64 + wave * 16;
  const int c0 = wave * 2, c1 = wave * 2 + 1;
  const int so = (lane * 16) ^ ((lane >> 3) << 4);   // within-chunk src byte

  bf16x8 qf[2];
#pragma unroll
  for (int h = 0; h < 2; ++h)
    qf[h] = *(const bf16x8*)&Qb[(size_t)(q0 + lr) * DHEAD + h * 32 + 8 * lg];
  f32x4 o[4] = {};
  float mrun = -INFINITY, lsum = 0.0f;
  const int nit = tile + 1;                  // 64-key blocks (uniform over waves)

  {
    const char* kg = (const char*)Kb;
    const char* vg = (const char*)Vb;
    gload_lds16(kg + c0 * 1024 + so, (char*)kbuf[0] + c0 * 1024);
    gload_lds16(kg + c1 * 1024 + so, (char*)kbuf[0] + c1 * 1024);
    gload_lds16(vg + c0 * 1024 + so, (char*)vbuf[0] + c0 * 1024);
    gload_lds16(vg + c1 * 1024 + so, (char*)vbuf[0] + c1 * 1024);
  }
  __syncthreads();
  int cur = 0;

  for (int it = 0; it < nit; ++it) {
    const int k0 = it * 64;
    if (it + 1 < nit) {                      // async-prefetch next tile
      const char* kg = (const char*)(Kb + (size_t)(k0 + 64) * DHEAD);
      const char* vg = (const char*)(Vb + (size_t)(it + 1) * 4096);
      char* kd = (char*)kbuf[cur ^ 1];
      char* vd = (char*)vbuf[cur ^ 1];
      gload_lds16(kg + c0 * 1024 + so, kd + c0 * 1024);
      gload_lds16(kg + c1 * 1024 + so, kd + c1 * 1024);
      gload_lds16(vg + c0 * 1024 + so, vd + c0 * 1024);
      gload_lds16(vg + c1 * 1024 + so, vd + c1 * 1024);
    }
    const char* kl = (const char*)kbuf[cur];
    const char* vl = (const char*)vbuf[cur];
    f32x4 s[4] = {};
#pragma unroll
    for (int c = 0; c < 4; ++c) {
      const int tr = c * 16 + lr;
      const int sw = (tr & 7) << 4;
      bf16x8 kf0 = *(const bf16x8*)(kl + tr * 128 + ((16 * lg) ^ sw));
      bf16x8 kf1 = *(const bf16x8*)(kl + tr * 128 + ((64 + 16 * lg) ^ sw));
      s[c] = __builtin_amdgcn_mfma_f32_16x16x32_bf16(kf0, qf[0], s[c], 0, 0, 0);
      s[c] = __builtin_amdgcn_mfma_f32_16x16x32_bf16(kf1, qf[1], s[c], 0, 0, 0);
    }
    const bool dm = (k0 + 63 > q0);
#pragma unroll
    for (int c = 0; c < 4; ++c)
#pragma unroll
      for (int i = 0; i < 4; ++i) {
        float sv = s[c][i] * 0.125f;
        if (dm && (k0 + c * 16 + lg * 4 + i > q0 + lr)) sv = -INFINITY;
        s[c][i] = sv;
      }
    float bm = s[0][0];
#pragma unroll
    for (int c = 0; c < 4; ++c)
#pragma unroll
      for (int i = 0; i < 4; ++i) bm = fmaxf(bm, s[c][i]);
    bm = fmaxf(bm, __shfl_xor(bm, 16));
    bm = fmaxf(bm, __shfl_xor(bm, 32));
    if (!__all(bm <= mrun)) {                // T13 defer-max
      const float mn = fmaxf(mrun, bm);
      const float al = __expf(mrun - mn);
      mrun = mn;
      lsum *= al;
#pragma unroll
      for (int dd = 0; dd < 4; ++dd)
#pragma unroll
        for (int i = 0; i < 4; ++i) o[dd][i] *= al;
    }
    float bs = 0.0f;
#pragma unroll
    for (int c = 0; c < 4; ++c)
#pragma unroll
      for (int i = 0; i < 4; ++i) {
        float e = __expf(s[c][i] - mrun);
        s[c][i] = e;
        bs += e;
      }
    bs += __shfl_xor(bs, 16);
    bs += __shfl_xor(bs, 32);
    lsum += bs;
#pragma unroll
    for (int c = 0; c < 4; ++c) {
      bf16x4 pb;
#pragma unroll
      for (int i = 0; i < 4; ++i) pb[i] = (bf16_t)s[c][i];
      const int byt = (lr * 128 + ((c * 32 + lg * 8) ^ ((lr & 7) << 4)));
      *(bf16x4*)(pwc + byt) = pb;
    }
    asm volatile("s_waitcnt lgkmcnt(0)" ::: "memory");
    __builtin_amdgcn_sched_barrier(0);
    bf16x8 pT[2];
#pragma unroll
    for (int h = 0; h < 2; ++h)
      pT[h] = *(const bf16x8*)(pwc + (lr * 128 + ((h * 64 + 16 * lg) ^ ((lr & 7) << 4))));
#pragma unroll
    for (int dd = 0; dd < 4; ++dd) {
      const int vr = dd * 16 + lr;
      const int sw = (vr & 7) << 4;
      bf16x8 vf0 = *(const bf16x8*)(vl + vr * 128 + ((16 * lg) ^ sw));
      bf16x8 vf1 = *(const bf16x8*)(vl + vr * 128 + ((64 + 16 * lg) ^ sw));
      o[dd] = __builtin_amdgcn_mfma_f32_16x16x32_bf16(vf0, pT[0], o[dd], 0, 0, 0);
      o[dd] = __builtin_amdgcn_mfma_f32_16x16x32_bf16(vf1, pT[1], o[dd], 0, 0, 0);
    }
    __syncthreads();                         // drains vmcnt -> next buffer ready
    cur ^= 1;
  }
  const float rls = 1.0f / lsum;
  bf16_t* orow = attn + (size_t)(b * T_SEQ + q0 + lr) * D_MODEL + hh * DHEAD;
#pragma unroll
  for (int dd = 0; dd < 4; ++dd) {
    bf16x4 ov;
#pragma unroll
    for (int i = 0; i < 4; ++i) ov[i] = (bf16_t)(o[dd][i] * rls);
    *(bf16x4*)(orow + dd * 16 + lg * 4) = ov;
  }
}

// ---------------- SwiGLU in-place on packed [4096][8192] buffer -------------
// a = cols 0..4095 (W1 out), b = cols 4096..8191 (W3 out); writes a-half.
__global__ __launch_bounds__(256) void swiglu_kernel(bf16_t* __restrict__ a13) {
  int i = blockIdx.x * 256 + threadIdx.x;   // 2M threads, 8 elems each
  int r = i >> 9;                           // 512 groups per 4096-col row
  int c = (i & 511) * 8;
  bf16_t* pa = a13 + (size_t)r * 8192 + c;
  bf16x8 va = *(const bf16x8*)pa;
  bf16x8 vb = *(const bf16x8*)(pa + 4096);
  bf16x8 og;
#pragma unroll
  for (int j = 0; j < 8; ++j) {
    float av = (float)va[j];
    float bv = (float)vb[j];
    float gv = av / (1.0f + __expf(-av)) * bv;
    og[j] = (bf16_t)gv;
  }
  *(bf16x8*)pa = og;
}

// ---------------- launch ----------------
extern "C" void kernel_launch(void* const* d_in, const int* in_sizes, int n_in,
                              void* d_out, int out_size, void* d_ws, size_t ws_size,
                              hipStream_t stream) {
  const float* x    = (const float*)d_in[0];
  const float* Wqkv = (const float*)d_in[1];
  const float* Wo   = (const float*)d_in[2];
  const float* g1   = (const float*)d_in[3];
  const float* g2   = (const float*)d_in[4];
  const float* W1   = (const float*)d_in[5];
  const float* W2   = (const float*)d_in[6];
  const float* W3   = (const float*)d_in[7];
  float* out = (float*)d_out;
  char* ws = (char*)d_ws;
  const size_t MB = 1024 * 1024;

  // workspace map (regions overlapped by liveness):
  float*  x1    = (float*)(ws + 0);          // [0,16M)  f32 residual-1 output
  bf16_t* h     = (bf16_t*)(ws + 16 * MB);   // [16,24M) rmsnorm1 out
  bf16_t* attn  = (bf16_t*)(ws + 16 * MB);   // reuse (h dead after QKV gemm)
  bf16_t* h2    = (bf16_t*)(ws + 16 * MB);   // reuse (attn dead after Wo gemm)
  bf16_t* qkv   = (bf16_t*)(ws + 24 * MB);   // [24,48M)
  bf16_t* Qb    = (bf16_t*)(ws + 48 * MB);   // [48,56M)
  bf16_t* Kb    = (bf16_t*)(ws + 56 * MB);   // [56,64M)
  bf16_t* Vt    = (bf16_t*)(ws + 64 * MB);   // [64,72M)  V tiled [bh][t64][d][64]
  bf16_t* ab13  = (bf16_t*)(ws + 24 * MB);   // [24,88M) packed W1|W3 out (qkv..Vt dead)
  bf16_t* wq_b  = (bf16_t*)(ws + 88 * MB);   // 6M
  bf16_t* wo_b  = (bf16_t*)(ws + 94 * MB);   // 2M
  bf16_t* w13_b = (bf16_t*)(ws + 96 * MB);   // 16M  [8192][1024] = W1 rows | W3 rows
  bf16_t* w2_b  = (bf16_t*)(ws + 112 * MB);  // 8M
  float*  cost  = (float*)(ws + 120 * MB);
  float*  sint  = (float*)(ws + 120 * MB + 262144);   // peak ~120.5M

  // fused weight conversion (1 launch)
  cvt_all_kernel<<<16384, 256, 0, stream>>>(Wqkv, Wo, W1, W3, W2, wq_b, wo_b, w13_b, w2_b);
  rope_tables_kernel<<<(T_SEQ * 32) / 256, 256, 0, stream>>>(cost, sint);

  // attention sub-block
  rmsnorm_kernel<<<ROWS, 256, 0, stream>>>(x, g1, h);
  gemm_bt<0, 128, 128><<<768, 256, 0, stream>>>(h, wq_b, qkv, nullptr,
                                                ROWS, 3 * D_MODEL, D_MODEL, D_MODEL, 24);
  rope_scatter_kernel<<<(BATCH * T_SEQ * NHEAD * 32) / 256, 256, 0, stream>>>(
      qkv, cost, sint, Qb, Kb);
  vt_kernel<<<dim3(T_SEQ / 64, BATCH * NHEAD), 256, 0, stream>>>(qkv, Vt);
  attn_kernel<<<1024, 256, 0, stream>>>(Qb, Kb, Vt, attn);
  gemm_bt<1, 128, 64><<<512, 256, 0, stream>>>(attn, wo_b, x1, x,
                                               ROWS, D_MODEL, D_MODEL, D_MODEL, 16);

  // FFN sub-block
  rmsnorm_kernel<<<ROWS, 256, 0, stream>>>(x1, g2, h2);
  gemm_bt<0, 128, 128><<<2048, 256, 0, stream>>>(h2, w13_b, ab13, nullptr,
                                                 ROWS, 2 * DFF, D_MODEL, D_MODEL, 64);
  swiglu_kernel<<<(ROWS * DFF) / (256 * 8), 256, 0, stream>>>(ab13);
  gemm_bt<1, 128, 64><<<512, 256, 0, stream>>>(ab13, w2_b, out, x1,
                                               ROWS, D_MODEL, DFF, 2 * DFF, 16);
}

// Round 7
// 418.736 us; speedup vs baseline: 1.5871x; 1.1313x over previous
//
#include <hip/hip_runtime.h>
#include <math.h>

typedef __bf16 bf16_t;
typedef __bf16 bf16x2 __attribute__((ext_vector_type(2)));
typedef __bf16 bf16x4 __attribute__((ext_vector_type(4)));
typedef __bf16 bf16x8 __attribute__((ext_vector_type(8)));
typedef float  f32x4  __attribute__((ext_vector_type(4)));

#define D_MODEL 1024
#define T_SEQ   2048
#define BATCH   2
#define NHEAD   16
#define DHEAD   64
#define DFF     4096
#define ROWS    (BATCH * T_SEQ)   // 4096

// ---------------- helpers ----------------
static __device__ __forceinline__ void gload_lds16(const void* g, void* l) {
  __builtin_amdgcn_global_load_lds((const __attribute__((address_space(1))) void*)g,
                                   (__attribute__((address_space(3))) void*)l,
                                   16, 0, 0);
}

// ---------------- fused f32 -> bf16 weight convert ----------------
// ranges in 4-float groups: Wqkv 786432 | Wo 262144 | W1 1048576 | W3 1048576 | W2 1048576
__global__ __launch_bounds__(256) void cvt_all_kernel(const float* __restrict__ Wqkv,
                                                      const float* __restrict__ Wo,
                                                      const float* __restrict__ W1,
                                                      const float* __restrict__ W3,
                                                      const float* __restrict__ W2,
                                                      bf16_t* __restrict__ wq,
                                                      bf16_t* __restrict__ wo,
                                                      bf16_t* __restrict__ w13,
                                                      bf16_t* __restrict__ w2) {
  int i = blockIdx.x * 256 + threadIdx.x;   // 4194304 groups total
  const float* src; bf16_t* dst; int off;
  if (i < 786432)       { src = Wqkv; dst = wq;            off = i; }
  else if (i < 1048576) { src = Wo;   dst = wo;            off = i - 786432; }
  else if (i < 2097152) { src = W1;   dst = w13;           off = i - 1048576; }
  else if (i < 3145728) { src = W3;   dst = w13 + 4194304; off = i - 2097152; }
  else                  { src = W2;   dst = w2;            off = i - 3145728; }
  float4 v = ((const float4*)src)[off];
  bf16x4 o;
  o[0] = (bf16_t)v.x; o[1] = (bf16_t)v.y; o[2] = (bf16_t)v.z; o[3] = (bf16_t)v.w;
  *(bf16x4*)(dst + off * 4) = o;
}

// ---------------- RoPE tables ----------------
__global__ __launch_bounds__(256) void rope_tables_kernel(float* __restrict__ cost,
                                                          float* __restrict__ sint) {
  int i = blockIdx.x * 256 + threadIdx.x;      // T_SEQ*32
  int t = i >> 5, p = i & 31;
  double inv = pow(10000.0, -(double)(2 * p) / 64.0);
  double ang = (double)t * inv;
  cost[i] = (float)cos(ang);
  sint[i] = (float)sin(ang);
}

// ---------------- RMSNorm (f32 in, bf16 out) ----------------
__global__ __launch_bounds__(256) void rmsnorm_kernel(const float* __restrict__ x,
                                                      const float* __restrict__ g,
                                                      bf16_t* __restrict__ out) {
  const int row = blockIdx.x;
  const int tid = threadIdx.x;          // 256 threads * 4 floats = 1024
  const float4 v = ((const float4*)(x + (size_t)row * D_MODEL))[tid];
  float ss = v.x * v.x + v.y * v.y + v.z * v.z + v.w * v.w;
#pragma unroll
  for (int m = 32; m >= 1; m >>= 1) ss += __shfl_xor(ss, m);
  __shared__ float red[4];
  if ((tid & 63) == 0) red[tid >> 6] = ss;
  __syncthreads();
  float tot = red[0] + red[1] + red[2] + red[3];
  const float rinv = 1.0f / sqrtf(tot * (1.0f / D_MODEL) + 1e-5f);
  const float4 gv = ((const float4*)g)[tid];
  bf16x4 o;
  o[0] = (bf16_t)(v.x * rinv * gv.x);
  o[1] = (bf16_t)(v.y * rinv * gv.y);
  o[2] = (bf16_t)(v.z * rinv * gv.z);
  o[3] = (bf16_t)(v.w * rinv * gv.w);
  *(bf16x4*)(out + (size_t)row * D_MODEL + tid * 4) = o;
}

// ---------------- RoPE apply + scatter qkv -> Q,K [B*H,T,dh] ----------------
__global__ __launch_bounds__(256) void rope_scatter_kernel(const bf16_t* __restrict__ qkv,
                                                           const float* __restrict__ cost,
                                                           const float* __restrict__ sint,
                                                           bf16_t* __restrict__ Q,
                                                           bf16_t* __restrict__ K) {
  int i = blockIdx.x * 256 + threadIdx.x;  // B*T*H*32 = 2^21
  int p = i & 31;
  int h = (i >> 5) & 15;
  int t = (i >> 9) & 2047;
  int b = i >> 20;
  const bf16_t* base = qkv + (size_t)(b * T_SEQ + t) * (3 * D_MODEL) + h * DHEAD + 2 * p;
  float qe = (float)base[0],            qo = (float)base[1];
  float ke = (float)base[D_MODEL],      ko = (float)base[D_MODEL + 1];
  float c = cost[t * 32 + p], s = sint[t * 32 + p];
  size_t o = ((size_t)(b * NHEAD + h) * T_SEQ + t) * DHEAD + 2 * p;
  bf16x2 qv, kv;
  qv[0] = (bf16_t)(qe * c - qo * s); qv[1] = (bf16_t)(qe * s + qo * c);
  kv[0] = (bf16_t)(ke * c - ko * s); kv[1] = (bf16_t)(ke * s + ko * c);
  *(bf16x2*)(Q + o) = qv;
  *(bf16x2*)(K + o) = kv;
}

// ---------------- V transpose: qkv V-part -> Vt[bh][t64][d][64] (tiled) -----
__global__ __launch_bounds__(256) void vt_kernel(const bf16_t* __restrict__ qkv,
                                                 bf16_t* __restrict__ Vt) {
  __shared__ bf16_t ld[64 * 72];
  const int tid = threadIdx.x;
  const int tt = blockIdx.x;           // 0..31 t-tiles
  const int bh = blockIdx.y;           // 0..31
  const int b = bh >> 4, h = bh & 15;
#pragma unroll
  for (int it = 0; it < 2; ++it) {
    int idx = it * 256 + tid;          // 0..511
    int r = idx >> 3, cc = (idx & 7) * 8;
    bf16x8 v = *(const bf16x8*)&qkv[(size_t)(b * T_SEQ + tt * 64 + r) * (3 * D_MODEL)
                                    + 2 * D_MODEL + h * DHEAD + cc];
    *(bf16x8*)&ld[r * 72 + cc] = v;
  }
  __syncthreads();
#pragma unroll
  for (int it = 0; it < 2; ++it) {
    int idx = it * 256 + tid;
    int d = idx >> 3, t8 = (idx & 7) * 8;
    bf16x8 v;
#pragma unroll
    for (int j = 0; j < 8; ++j) v[j] = ld[(t8 + j) * 72 + d];
    *(bf16x8*)&Vt[(((size_t)bh * 32 + tt) * 64 + d) * 64 + t8] = v;
  }
}

// ======== 256x256 8-wave phase-scheduled GEMM: C[M,N] = A * B^T (bf16 out) ==
// BK=64, 512 threads as 2x4 waves (wave output 128x64). LDS 128KB (2x dbuf).
// Per K-tile: 4 quadrant-phases {12 ds_read_b128 | stage halftiles | s_barrier
// | lgkmcnt(0) | setprio(1) 16 MFMA setprio(0) | barrier}. Only vmcnt wait is
// at the tile boundary (outstanding == exactly next tile's 8 loads, issued
// 2-3 phases earlier -> latency hidden; prefetch never drained early).
// LDS XOR-swizzle (T2) via rule 21: linear gload dest + inverse-swizzled
// global source + swizzled ds_read (byte ^ ((row&7)<<4)).
__global__ __launch_bounds__(512, 2) void gemm256(const bf16_t* __restrict__ A,
                                                  const bf16_t* __restrict__ B,
                                                  bf16_t* __restrict__ C,
                                                  int M, int N, int K, int lda, int gxn) {
  __shared__ __align__(16) bf16_t lA[2][256 * 64];
  __shared__ __align__(16) bf16_t lB[2][256 * 64];
  const int tid = threadIdx.x;
  const int wave = tid >> 6, lane = tid & 63;
  const int lr = lane & 15, lg = lane >> 4;
  const int wm = wave >> 2, wn = wave & 3;       // 2x4 wave grid
  const int nwg = gridDim.x;
  const int bid = blockIdx.x;
  const int swz = (bid & 7) * (nwg >> 3) + (bid >> 3);
  const int bx = swz % gxn, by = swz / gxn;
  const int brow = by * 256, bcol = bx * 256;
  const bf16_t* __restrict__ Ab = A + (size_t)brow * lda;
  const bf16_t* __restrict__ Bb = B + (size_t)bcol * K;
  const int NT = K >> 6;

  // stage one 16KB half-tile (rows hh*128..hh*128+127) of a [256][64] tile
  auto stage_half = [&](const bf16_t* __restrict__ G, int ld, int k0, char* lbuf, int hh) {
#pragma unroll
    for (int r = 0; r < 2; ++r) {
      const int db = hh * 16384 + r * 8192 + wave * 1024;   // uniform per wave
      const int d = db + lane * 16;
      const int row = d >> 7;
      const int cb = (d & 127) ^ ((row & 7) << 4);          // inverse-swizzled src
      gload_lds16((const char*)(G + (size_t)row * ld + k0) + cb, lbuf + db);
    }
  };

  f32x4 acc[8][4] = {};

  // prologue: stage tile 0
  stage_half(Ab, lda, 0, (char*)lA[0], 0);
  stage_half(Ab, lda, 0, (char*)lA[0], 1);
  stage_half(Bb, K, 0, (char*)lB[0], 0);
  stage_half(Bb, K, 0, (char*)lB[0], 1);
  asm volatile("s_waitcnt vmcnt(0)" ::: "memory");
  __builtin_amdgcn_s_barrier();

  for (int t = 0; t < NT; ++t) {
    const int p = t & 1;
    const int k0 = t * 64;
    const char* pA = (const char*)lA[p];
    const char* pB = (const char*)lB[p];
    char* nA = (char*)lA[p ^ 1];
    char* nB = (char*)lB[p ^ 1];
#pragma unroll
    for (int q = 0; q < 4; ++q) {
      const int qr = q >> 1, qc = q & 1;
      bf16x8 aF[4][2], bF[2][2];
#pragma unroll
      for (int mi = 0; mi < 4; ++mi) {
        const int ar = wm * 128 + qr * 64 + mi * 16 + lr;
#pragma unroll
        for (int h = 0; h < 2; ++h)
          aF[mi][h] = *(const bf16x8*)(pA + ar * 128 + ((h * 64 + lg * 16) ^ ((ar & 7) << 4)));
      }
#pragma unroll
      for (int ni = 0; ni < 2; ++ni) {
        const int br_ = wn * 64 + qc * 32 + ni * 16 + lr;
#pragma unroll
        for (int h = 0; h < 2; ++h)
          bF[ni][h] = *(const bf16x8*)(pB + br_ * 128 + ((h * 64 + lg * 16) ^ ((br_ & 7) << 4)));
      }
      if (t + 1 < NT) {                       // front-loaded prefetch (q0: A, q1: B)
        if (q == 0) {
          stage_half(Ab, lda, k0 + 64, nA, 0);
          stage_half(Ab, lda, k0 + 64, nA, 1);
        } else if (q == 1) {
          stage_half(Bb, K, k0 + 64, nB, 0);
          stage_half(Bb, K, k0 + 64, nB, 1);
        }
      }
      __builtin_amdgcn_s_barrier();
      asm volatile("s_waitcnt lgkmcnt(0)" ::: "memory");
      __builtin_amdgcn_sched_barrier(0);
      __builtin_amdgcn_s_setprio(1);
#pragma unroll
      for (int h = 0; h < 2; ++h)
#pragma unroll
        for (int mi = 0; mi < 4; ++mi)
#pragma unroll
          for (int ni = 0; ni < 2; ++ni)
            acc[qr * 4 + mi][qc * 2 + ni] = __builtin_amdgcn_mfma_f32_16x16x32_bf16(
                aF[mi][h], bF[ni][h], acc[qr * 4 + mi][qc * 2 + ni], 0, 0, 0);
      __builtin_amdgcn_s_setprio(0);
      if (q == 3 && t + 1 < NT)               // boundary: wait next tile's loads
        asm volatile("s_waitcnt vmcnt(0)" ::: "memory");
      __builtin_amdgcn_s_barrier();
    }
  }
  // epilogue: C/D layout col=lane&15, row=lg*4+i
#pragma unroll
  for (int Mi = 0; Mi < 8; ++Mi)
#pragma unroll
    for (int Ni = 0; Ni < 4; ++Ni)
#pragma unroll
      for (int i = 0; i < 4; ++i)
        C[(size_t)(brow + wm * 128 + Mi * 16 + lg * 4 + i) * N + bcol + wn * 64 + Ni * 16 + lr] =
            (bf16_t)acc[Mi][Ni][i];
}

// ---------------- GEMM (2-phase, 4 waves): C = A * B^T (+ res, f32 out) -----
// Used for the small-N GEMMs (Wo, W2). Now with T2 XOR swizzle (rule 21).
template <int EPI, int BM, int BN>
__global__ __launch_bounds__(256) void gemm_bt(const bf16_t* __restrict__ A,
                                               const bf16_t* __restrict__ B,
                                               void* __restrict__ Cout,
                                               const float* __restrict__ res,
                                               int M, int N, int K, int lda, int gxn) {
  constexpr int MR = BM / 32, NR = BN / 32;
  __shared__ __align__(16) bf16_t lA[BM * 64];
  __shared__ __align__(16) bf16_t lB[BN * 64];
  const int tid = threadIdx.x;
  const int wave = tid >> 6, lane = tid & 63;
  const int lr = lane & 15, lg = lane >> 4;
  const int nwg = gridDim.x;
  const int bid = blockIdx.x;
  const int swz = (bid & 7) * (nwg >> 3) + (bid >> 3);
  const int bx = swz % gxn, by = swz / gxn;
  const int brow = by * BM, bcol = bx * BN;
  const int wr = (wave >> 1) * (BM / 2), wc = (wave & 1) * (BN / 2);
  f32x4 acc[MR][NR] = {};
  for (int k0 = 0; k0 < K; k0 += 64) {
    __syncthreads();  // protect LDS from previous iteration's readers
#pragma unroll
    for (int r = 0; r < BM / 32; ++r) {
      const int base = r * 4096 + wave * 1024;
      const int fb = base + lane * 16;
      const int row = fb >> 7;
      const int cb = (fb & 127) ^ ((row & 7) << 4);
      gload_lds16((const char*)(A + (size_t)(brow + row) * lda + k0) + cb, (char*)lA + base);
    }
#pragma unroll
    for (int r = 0; r < BN / 32; ++r) {
      const int base = r * 4096 + wave * 1024;
      const int fb = base + lane * 16;
      const int row = fb >> 7;
      const int cb = (fb & 127) ^ ((row & 7) << 4);
      gload_lds16((const char*)(B + (size_t)(bcol + row) * K + k0) + cb, (char*)lB + base);
    }
    __syncthreads();  // staging complete
    bf16x8 aF[MR][2], bF[NR][2];
#pragma unroll
    for (int mi = 0; mi < MR; ++mi) {
      const int ar = wr + mi * 16 + lr;
#pragma unroll
      for (int h = 0; h < 2; ++h)
        aF[mi][h] = *(const bf16x8*)((const char*)lA + ar * 128 + ((h * 64 + lg * 16) ^ ((ar & 7) << 4)));
    }
#pragma unroll
    for (int ni = 0; ni < NR; ++ni) {
      const int br_ = wc + ni * 16 + lr;
#pragma unroll
      for (int h = 0; h < 2; ++h)
        bF[ni][h] = *(const bf16x8*)((const char*)lB + br_ * 128 + ((h * 64 + lg * 16) ^ ((br_ & 7) << 4)));
    }
#pragma unroll
    for (int h = 0; h < 2; ++h)
#pragma unroll
      for (int mi = 0; mi < MR; ++mi)
#pragma unroll
        for (int ni = 0; ni < NR; ++ni)
          acc[mi][ni] = __builtin_amdgcn_mfma_f32_16x16x32_bf16(aF[mi][h], bF[ni][h], acc[mi][ni], 0, 0, 0);
  }
  const int rb = brow + wr + lg * 4;
  const int cb2 = bcol + wc + lr;
  if (EPI == 0) {
    bf16_t* C = (bf16_t*)Cout;
#pragma unroll
    for (int mi = 0; mi < MR; ++mi)
#pragma unroll
      for (int ni = 0; ni < NR; ++ni)
#pragma unroll
        for (int i = 0; i < 4; ++i)
          C[(size_t)(rb + mi * 16 + i) * N + cb2 + ni * 16] = (bf16_t)acc[mi][ni][i];
  } else {
    float* C = (float*)Cout;
#pragma unroll
    for (int mi = 0; mi < MR; ++mi)
#pragma unroll
      for (int ni = 0; ni < NR; ++ni)
#pragma unroll
        for (int i = 0; i < 4; ++i) {
          size_t idx = (size_t)(rb + mi * 16 + i) * N + cb2 + ni * 16;
          C[idx] = acc[mi][ni][i] + res[idx];
        }
  }
}

// ---------------- causal flash attention v5 (LDS-staged K/V, dbuf) ----------
__global__ __launch_bounds__(256, 4) void attn_kernel(const bf16_t* __restrict__ Q,
                                                      const bf16_t* __restrict__ K,
                                                      const bf16_t* __restrict__ Vt,
                                                      bf16_t* __restrict__ attn) {
  __shared__ __align__(16) bf16_t kbuf[2][64 * 64];
  __shared__ __align__(16) bf16_t vbuf[2][64 * 64];
  __shared__ __align__(16) bf16_t pbuf[4][16 * 64];
  const int tid = threadIdx.x;
  const int wave = tid >> 6, lane = tid & 63;
  const int lr = lane & 15, lg = lane >> 4;
  const int bid = blockIdx.x;
  const int x = bid & 7, u = bid >> 3;       // u: 0..127
  const int bh = x * 4 + (u & 3);            // XCD x owns bh 4x..4x+3
  const int v = u >> 2;                      // 0..31
  const int tile = (7 * v + 5 * (u & 3) + x) & 31;   // hashed bijection per bh
  const int b = bh >> 4, hh = bh & 15;
  const size_t hb = (size_t)bh * T_SEQ * DHEAD;
  const bf16_t* Qb = Q + hb;
  const bf16_t* Kb = K + hb;
  const bf16_t* Vb = Vt + hb;                // [32][64][64]
  char* pwc = (char*)pbuf[wave];
  const int q0 = tile * 64 + wave * 16;
  const int c0 = wave * 2, c1 = wave * 2 + 1;
  const int so = (lane * 16) ^ ((lane >> 3) << 4);   // within-chunk src byte

  bf16x8 qf[2];
#pragma unroll
  for (int h = 0; h < 2; ++h)
    qf[h] = *(const bf16x8*)&Qb[(size_t)(q0 + lr) * DHEAD + h * 32 + 8 * lg];
  f32x4 o[4] = {};
  float mrun = -INFINITY, lsum = 0.0f;
  const int nit = tile + 1;                  // 64-key blocks (uniform over waves)

  {
    const char* kg = (const char*)Kb;
    const char* vg = (const char*)Vb;
    gload_lds16(kg + c0 * 1024 + so, (char*)kbuf[0] + c0 * 1024);
    gload_lds16(kg + c1 * 1024 + so, (char*)kbuf[0] + c1 * 1024);
    gload_lds16(vg + c0 * 1024 + so, (char*)vbuf[0] + c0 * 1024);
    gload_lds16(vg + c1 * 1024 + so, (char*)vbuf[0] + c1 * 1024);
  }
  __syncthreads();
  int cur = 0;

  for (int it = 0; it < nit; ++it) {
    const int k0 = it * 64;
    if (it + 1 < nit) {                      // async-prefetch next tile
      const char* kg = (const char*)(Kb + (size_t)(k0 + 64) * DHEAD);
      const char* vg = (const char*)(Vb + (size_t)(it + 1) * 4096);
      char* kd = (char*)kbuf[cur ^ 1];
      char* vd = (char*)vbuf[cur ^ 1];
      gload_lds16(kg + c0 * 1024 + so, kd + c0 * 1024);
      gload_lds16(kg + c1 * 1024 + so, kd + c1 * 1024);
      gload_lds16(vg + c0 * 1024 + so, vd + c0 * 1024);
      gload_lds16(vg + c1 * 1024 + so, vd + c1 * 1024);
    }
    const char* kl = (const char*)kbuf[cur];
    const char* vl = (const char*)vbuf[cur];
    f32x4 s[4] = {};
#pragma unroll
    for (int c = 0; c < 4; ++c) {
      const int tr = c * 16 + lr;
      const int sw = (tr & 7) << 4;
      bf16x8 kf0 = *(const bf16x8*)(kl + tr * 128 + ((16 * lg) ^ sw));
      bf16x8 kf1 = *(const bf16x8*)(kl + tr * 128 + ((64 + 16 * lg) ^ sw));
      s[c] = __builtin_amdgcn_mfma_f32_16x16x32_bf16(kf0, qf[0], s[c], 0, 0, 0);
      s[c] = __builtin_amdgcn_mfma_f32_16x16x32_bf16(kf1, qf[1], s[c], 0, 0, 0);
    }
    const bool dm = (k0 + 63 > q0);
#pragma unroll
    for (int c = 0; c < 4; ++c)
#pragma unroll
      for (int i = 0; i < 4; ++i) {
        float sv = s[c][i] * 0.125f;
        if (dm && (k0 + c * 16 + lg * 4 + i > q0 + lr)) sv = -INFINITY;
        s[c][i] = sv;
      }
    float bm = s[0][0];
#pragma unroll
    for (int c = 0; c < 4; ++c)
#pragma unroll
      for (int i = 0; i < 4; ++i) bm = fmaxf(bm, s[c][i]);
    bm = fmaxf(bm, __shfl_xor(bm, 16));
    bm = fmaxf(bm, __shfl_xor(bm, 32));
    if (!__all(bm <= mrun)) {                // T13 defer-max
      const float mn = fmaxf(mrun, bm);
      const float al = __expf(mrun - mn);
      mrun = mn;
      lsum *= al;
#pragma unroll
      for (int dd = 0; dd < 4; ++dd)
#pragma unroll
        for (int i = 0; i < 4; ++i) o[dd][i] *= al;
    }
    float bs = 0.0f;
#pragma unroll
    for (int c = 0; c < 4; ++c)
#pragma unroll
      for (int i = 0; i < 4; ++i) {
        float e = __expf(s[c][i] - mrun);
        s[c][i] = e;
        bs += e;
      }
    bs += __shfl_xor(bs, 16);
    bs += __shfl_xor(bs, 32);
    lsum += bs;
#pragma unroll
    for (int c = 0; c < 4; ++c) {
      bf16x4 pb;
#pragma unroll
      for (int i = 0; i < 4; ++i) pb[i] = (bf16_t)s[c][i];
      const int byt = (lr * 128 + ((c * 32 + lg * 8) ^ ((lr & 7) << 4)));
      *(bf16x4*)(pwc + byt) = pb;
    }
    asm volatile("s_waitcnt lgkmcnt(0)" ::: "memory");
    __builtin_amdgcn_sched_barrier(0);
    bf16x8 pT[2];
#pragma unroll
    for (int h = 0; h < 2; ++h)
      pT[h] = *(const bf16x8*)(pwc + (lr * 128 + ((h * 64 + 16 * lg) ^ ((lr & 7) << 4))));
#pragma unroll
    for (int dd = 0; dd < 4; ++dd) {
      const int vr = dd * 16 + lr;
      const int sw = (vr & 7) << 4;
      bf16x8 vf0 = *(const bf16x8*)(vl + vr * 128 + ((16 * lg) ^ sw));
      bf16x8 vf1 = *(const bf16x8*)(vl + vr * 128 + ((64 + 16 * lg) ^ sw));
      o[dd] = __builtin_amdgcn_mfma_f32_16x16x32_bf16(vf0, pT[0], o[dd], 0, 0, 0);
      o[dd] = __builtin_amdgcn_mfma_f32_16x16x32_bf16(vf1, pT[1], o[dd], 0, 0, 0);
    }
    __syncthreads();                         // drains vmcnt -> next buffer ready
    cur ^= 1;
  }
  const float rls = 1.0f / lsum;
  bf16_t* orow = attn + (size_t)(b * T_SEQ + q0 + lr) * D_MODEL + hh * DHEAD;
#pragma unroll
  for (int dd = 0; dd < 4; ++dd) {
    bf16x4 ov;
#pragma unroll
    for (int i = 0; i < 4; ++i) ov[i] = (bf16_t)(o[dd][i] * rls);
    *(bf16x4*)(orow + dd * 16 + lg * 4) = ov;
  }
}

// ---------------- SwiGLU in-place on packed [4096][8192] buffer -------------
// a = cols 0..4095 (W1 out), b = cols 4096..8191 (W3 out); writes a-half.
__global__ __launch_bounds__(256) void swiglu_kernel(bf16_t* __restrict__ a13) {
  int i = blockIdx.x * 256 + threadIdx.x;   // 2M threads, 8 elems each
  int r = i >> 9;                           // 512 groups per 4096-col row
  int c = (i & 511) * 8;
  bf16_t* pa = a13 + (size_t)r * 8192 + c;
  bf16x8 va = *(const bf16x8*)pa;
  bf16x8 vb = *(const bf16x8*)(pa + 4096);
  bf16x8 og;
#pragma unroll
  for (int j = 0; j < 8; ++j) {
    float av = (float)va[j];
    float bv = (float)vb[j];
    float gv = av / (1.0f + __expf(-av)) * bv;
    og[j] = (bf16_t)gv;
  }
  *(bf16x8*)pa = og;
}

// ---------------- launch ----------------
extern "C" void kernel_launch(void* const* d_in, const int* in_sizes, int n_in,
                              void* d_out, int out_size, void* d_ws, size_t ws_size,
                              hipStream_t stream) {
  const float* x    = (const float*)d_in[0];
  const float* Wqkv = (const float*)d_in[1];
  const float* Wo   = (const float*)d_in[2];
  const float* g1   = (const float*)d_in[3];
  const float* g2   = (const float*)d_in[4];
  const float* W1   = (const float*)d_in[5];
  const float* W2   = (const float*)d_in[6];
  const float* W3   = (const float*)d_in[7];
  float* out = (float*)d_out;
  char* ws = (char*)d_ws;
  const size_t MB = 1024 * 1024;

  // workspace map (regions overlapped by liveness):
  float*  x1    = (float*)(ws + 0);          // [0,16M)  f32 residual-1 output
  bf16_t* h     = (bf16_t*)(ws + 16 * MB);   // [16,24M) rmsnorm1 out
  bf16_t* attn  = (bf16_t*)(ws + 16 * MB);   // reuse (h dead after QKV gemm)
  bf16_t* h2    = (bf16_t*)(ws + 16 * MB);   // reuse (attn dead after Wo gemm)
  bf16_t* qkv   = (bf16_t*)(ws + 24 * MB);   // [24,48M)
  bf16_t* Qb    = (bf16_t*)(ws + 48 * MB);   // [48,56M)
  bf16_t* Kb    = (bf16_t*)(ws + 56 * MB);   // [56,64M)
  bf16_t* Vt    = (bf16_t*)(ws + 64 * MB);   // [64,72M)  V tiled [bh][t64][d][64]
  bf16_t* ab13  = (bf16_t*)(ws + 24 * MB);   // [24,88M) packed W1|W3 out (qkv..Vt dead)
  bf16_t* wq_b  = (bf16_t*)(ws + 88 * MB);   // 6M
  bf16_t* wo_b  = (bf16_t*)(ws + 94 * MB);   // 2M
  bf16_t* w13_b = (bf16_t*)(ws + 96 * MB);   // 16M  [8192][1024] = W1 rows | W3 rows
  bf16_t* w2_b  = (bf16_t*)(ws + 112 * MB);  // 8M
  float*  cost  = (float*)(ws + 120 * MB);
  float*  sint  = (float*)(ws + 120 * MB + 262144);   // peak ~120.5M

  // fused weight conversion (1 launch)
  cvt_all_kernel<<<16384, 256, 0, stream>>>(Wqkv, Wo, W1, W3, W2, wq_b, wo_b, w13_b, w2_b);
  rope_tables_kernel<<<(T_SEQ * 32) / 256, 256, 0, stream>>>(cost, sint);

  // attention sub-block
  rmsnorm_kernel<<<ROWS, 256, 0, stream>>>(x, g1, h);
  gemm256<<<192, 512, 0, stream>>>(h, wq_b, qkv, ROWS, 3 * D_MODEL, D_MODEL, D_MODEL, 12);
  rope_scatter_kernel<<<(BATCH * T_SEQ * NHEAD * 32) / 256, 256, 0, stream>>>(
      qkv, cost, sint, Qb, Kb);
  vt_kernel<<<dim3(T_SEQ / 64, BATCH * NHEAD), 256, 0, stream>>>(qkv, Vt);
  attn_kernel<<<1024, 256, 0, stream>>>(Qb, Kb, Vt, attn);
  gemm_bt<1, 128, 64><<<512, 256, 0, stream>>>(attn, wo_b, x1, x,
                                               ROWS, D_MODEL, D_MODEL, D_MODEL, 16);

  // FFN sub-block
  rmsnorm_kernel<<<ROWS, 256, 0, stream>>>(x1, g2, h2);
  gemm256<<<512, 512, 0, stream>>>(h2, w13_b, ab13, ROWS, 2 * DFF, D_MODEL, D_MODEL, 32);
  swiglu_kernel<<<(ROWS * DFF) / (256 * 8), 256, 0, stream>>>(ab13);
  gemm_bt<1, 128, 64><<<512, 256, 0, stream>>>(ab13, w2_b, out, x1,
                                               ROWS, D_MODEL, DFF, 2 * DFF, 16);
}